// Round 7
// baseline (203.024 us; speedup 1.0000x reference)
//
#include <hip/hip_runtime.h>
#include <hip/hip_bf16.h>

#define Cc 64
#define Hc 128
#define Wc 128
#define HWc (Hc * Wc)
#define Bc 4

typedef __attribute__((ext_vector_type(8))) short short8;
typedef __attribute__((ext_vector_type(4))) float float4v;

static __device__ __forceinline__ unsigned short f2bu(float f) {
    __hip_bfloat16 h = __float2bfloat16(f);
    return *(unsigned short*)&h;
}

// ---------------------------------------------------------------------------
// Merged NCHW f32 -> NHWC bf16 for x (fused ReLU) and kf. grid = 512.
// ---------------------------------------------------------------------------
__global__ __launch_bounds__(256) void cvt_both_k(
    const float* __restrict__ x, const float* __restrict__ kf,
    unsigned short* __restrict__ xb, unsigned short* __restrict__ kfb)
{
    const int bid = blockIdx.x;
    const bool isx = bid < 256;
    const float* src = isx ? x : kf;
    unsigned short* dst = isx ? xb : kfb;
    const int px = (isx ? bid : bid - 256) * 256 + threadIdx.x;
    const int b  = px >> 14;
    const int hw = px & 16383;
    const float* s = src + (size_t)b * Cc * HWc + hw;
    unsigned short* d = dst + (size_t)px * Cc;

#pragma unroll
    for (int c8 = 0; c8 < 8; ++c8) {
        unsigned int pk[4];
#pragma unroll
        for (int jp = 0; jp < 4; ++jp) {
            float v0 = s[(size_t)(c8 * 8 + jp * 2 + 0) * HWc];
            float v1 = s[(size_t)(c8 * 8 + jp * 2 + 1) * HWc];
            if (isx) { v0 = fmaxf(v0, 0.f); v1 = fmaxf(v1, 0.f); }
            pk[jp] = (unsigned int)f2bu(v0) | ((unsigned int)f2bu(v1) << 16);
        }
        *(uint4*)(d + c8 * 8) = make_uint4(pk[0], pk[1], pk[2], pk[3]);
    }
}

// ---------------------------------------------------------------------------
// All weight packing in one launch (as round 5/6).
// ---------------------------------------------------------------------------
__global__ __launch_bounds__(256) void wpack_all_k(
    const float* __restrict__ fw1, const float* __restrict__ fw2,
    const float* __restrict__ mw1, const float* __restrict__ mw2,
    const float* __restrict__ lw1, const float* __restrict__ lw2,
    unsigned short* __restrict__ wbase)
{
    const int bid = blockIdx.x;
    const int tid = threadIdx.x;
    if (bid < 72) {
        const int which = bid / 18;
        const float* w = (which == 0) ? fw1 : (which == 1) ? fw2 : (which == 2) ? mw1 : mw2;
        unsigned short* wb = wbase + (size_t)which * 36864;
        const int g = (bid % 18) * 256 + tid;
        if (g >= 4608) return;
        const int lane = g & 63;
        const int smt  = g >> 6;
        const int s    = smt >> 2;
        const int mt   = smt & 3;
        const int co   = mt * 16 + (lane & 15);
        const int kb   = s * 32 + (lane >> 4) * 8;
        unsigned int pk[4];
#pragma unroll
        for (int jp = 0; jp < 4; ++jp) {
            int k0 = kb + jp * 2, k1 = k0 + 1;
            float v0 = w[((size_t)co * Cc + (k0 & 63)) * 9 + (k0 >> 6)];
            float v1 = w[((size_t)co * Cc + (k1 & 63)) * 9 + (k1 >> 6)];
            pk[jp] = (unsigned int)f2bu(v0) | ((unsigned int)f2bu(v1) << 16);
        }
        *(uint4*)(wb + (size_t)g * 8) = make_uint4(pk[0], pk[1], pk[2], pk[3]);
    } else {
        const int which = (bid - 72) >> 1;
        const float* w = which ? lw2 : lw1;
        const int Cout = which ? 49 : 64;
        unsigned short* wb = wbase + 4 * 36864 + (size_t)which * 4096;
        const int g = ((bid - 72) & 1) * 256 + tid;
        const int lane = g & 63;
        const int smt  = g >> 6;
        const int s    = smt >> 2;
        const int mt   = smt & 3;
        const int co   = mt * 16 + (lane & 15);
        const int kb   = s * 32 + (lane >> 4) * 8;
        unsigned int pk[4];
#pragma unroll
        for (int jp = 0; jp < 4; ++jp) {
            int k0 = kb + jp * 2, k1 = k0 + 1;
            float v0 = (co < Cout) ? w[(size_t)co * Cc + k0] : 0.f;
            float v1 = (co < Cout) ? w[(size_t)co * Cc + k1] : 0.f;
            pk[jp] = (unsigned int)f2bu(v0) | ((unsigned int)f2bu(v1) << 16);
        }
        *(uint4*)(wb + (size_t)g * 8) = make_uint4(pk[0], pk[1], pk[2], pk[3]);
    }
}

// ===== shared staging + pipelined-GEMM building blocks (macros) ============
#define STAGE_TILE(INPTR)                                                     \
    for (int u = tid; u < 264; u += 256) {                                    \
        const int r_  = u / 66;                                               \
        const int c_  = u - r_ * 66;                                          \
        const int gh_ = h0 - 1 + r_;                                          \
        const int gw_ = w0 - 1 + c_;                                          \
        const bool ok_ = ((unsigned)gh_ < (unsigned)Hc) && ((unsigned)gw_ < (unsigned)Wc); \
        const unsigned short* src_ =                                          \
            (INPTR) + (((size_t)b * Hc + (ok_ ? gh_ : 0)) * Wc + (ok_ ? gw_ : 0)) * Cc; \
        const int sw_ = u & 7;                                                \
        _Pragma("unroll")                                                     \
        for (int ch_ = 0; ch_ < 8; ++ch_) {                                   \
            uint4 v_ = ok_ ? *(const uint4*)(src_ + ch_ * 8) : make_uint4(0, 0, 0, 0); \
            *(uint4*)&s_b[u * 64 + ((ch_ ^ sw_) << 3)] = v_;                  \
        }                                                                     \
    }

#define LOAD_A(W, s, m) (*(const short8*)((W) + (size_t)(s) * 2048 + (size_t)(m) * 512))
#define LOAD_B(s, nt) ({                                                      \
        const int tap_ = (s) >> 1;                                            \
        const int qb_  = rowb[tap_ / 3] + tap_ % 3;                           \
        const int ch0_ = ((s) & 1) * 4 + quad;                                \
        *(const short8*)&s_b[(qb_ + (nt) * 16) * 64 + ((ch0_ ^ (qb_ & 7)) << 3)]; })

#define CONV_GEMM(APTR, ACC)                                                  \
    {                                                                         \
        short8 a_cur[2], b_cur[4];                                            \
        _Pragma("unroll")                                                     \
        for (int m = 0; m < 2; ++m) a_cur[m] = LOAD_A(APTR, 0, m);            \
        _Pragma("unroll")                                                     \
        for (int nt = 0; nt < 4; ++nt) b_cur[nt] = LOAD_B(0, nt);             \
        _Pragma("unroll")                                                     \
        for (int s = 0; s < 18; ++s) {                                        \
            short8 a_nxt[2], b_nxt[4];                                        \
            if (s < 17) {                                                     \
                _Pragma("unroll")                                             \
                for (int m = 0; m < 2; ++m) a_nxt[m] = LOAD_A(APTR, s + 1, m);\
                _Pragma("unroll")                                             \
                for (int nt = 0; nt < 4; ++nt) b_nxt[nt] = LOAD_B(s + 1, nt); \
            }                                                                 \
            _Pragma("unroll")                                                 \
            for (int nt = 0; nt < 4; ++nt)                                    \
                _Pragma("unroll")                                             \
                for (int m = 0; m < 2; ++m)                                   \
                    ACC[m][nt] = __builtin_amdgcn_mfma_f32_16x16x32_bf16(     \
                        a_cur[m], b_cur[nt], ACC[m][nt], 0, 0, 0);            \
            if (s < 17) {                                                     \
                _Pragma("unroll")                                             \
                for (int m = 0; m < 2; ++m) a_cur[m] = a_nxt[m];              \
                _Pragma("unroll")                                             \
                for (int nt = 0; nt < 4; ++nt) b_cur[nt] = b_nxt[nt];         \
            }                                                                 \
        }                                                                     \
    }

// ---------------------------------------------------------------------------
// conv1 dual dispatch (round-6 conv3x3_v4, DUAL config only): both paths'
// first conv, relu-out, bf16 NHWC out. grid = (W/64, H/2, 2*B).
// ---------------------------------------------------------------------------
__global__ __launch_bounds__(256) void conv1_dual_k(
    const unsigned short* __restrict__ in0,
    const unsigned short* __restrict__ in1,
    const unsigned short* __restrict__ wfrag0,
    const unsigned short* __restrict__ wfrag1,
    const float* __restrict__ bias0,
    const float* __restrict__ bias1,
    unsigned short* __restrict__ out0,
    unsigned short* __restrict__ out1)
{
    __shared__ unsigned short s_b[264 * 64];

    const int tid  = threadIdx.x;
    const int lane = tid & 63;
    const int wv   = tid >> 6;
    const int w0   = blockIdx.x * 64;
    const int h0   = blockIdx.y * 2;
    const int zz   = blockIdx.z;
    const int b    = zz & 3;
    const bool sel = zz >> 2;

    const unsigned short* in    = sel ? in1 : in0;
    const unsigned short* wfrag = sel ? wfrag1 : wfrag0;
    const float*          bias  = sel ? bias1 : bias0;
    unsigned short*       out   = sel ? out1 : out0;

    STAGE_TILE(in);
    __syncthreads();

    const int rowsel = wv >> 1;
    const int cohalf = wv & 1;
    const int quad   = lane >> 4;
    const int n15    = lane & 15;
    const unsigned short* aptr = wfrag + (((size_t)(cohalf * 2) * 64 + lane) << 3);

    int rowb[3];
#pragma unroll
    for (int ky = 0; ky < 3; ++ky) rowb[ky] = (rowsel + ky) * 66 + n15;

    float4v acc[2][4];
#pragma unroll
    for (int m = 0; m < 2; ++m)
#pragma unroll
        for (int nt = 0; nt < 4; ++nt) acc[m][nt] = (float4v){0.f, 0.f, 0.f, 0.f};

    CONV_GEMM(aptr, acc);

    const int h = h0 + rowsel;
#pragma unroll
    for (int m = 0; m < 2; ++m) {
        const int mt  = cohalf * 2 + m;
        const int co0 = mt * 16 + quad * 4;
        float4 bv = *(const float4*)&bias[co0];
#pragma unroll
        for (int nt = 0; nt < 4; ++nt) {
            const size_t pix = ((size_t)b * Hc + h) * Wc + w0 + nt * 16 + n15;
            ushort4 pk;
            pk.x = f2bu(fmaxf(acc[m][nt][0] + bv.x, 0.f));
            pk.y = f2bu(fmaxf(acc[m][nt][1] + bv.y, 0.f));
            pk.z = f2bu(fmaxf(acc[m][nt][2] + bv.z, 0.f));
            pk.w = f2bu(fmaxf(acc[m][nt][3] + bv.w, 0.f));
            *(ushort4*)&out[pix * Cc + co0] = pk;
        }
    }
}

// ---------------------------------------------------------------------------
// conv2 fused: fp = conv(t1f)+fb2 (kept in regs, bf16-rounded), then
// mp = conv(t1m)+mb2, feat = fp*mp -> f32 NCHW. Same tiling as conv1.
// grid = (W/64, H/2, B).
// ---------------------------------------------------------------------------
__global__ __launch_bounds__(256) void conv2_fused_k(
    const unsigned short* __restrict__ t1f,
    const unsigned short* __restrict__ t1m,
    const unsigned short* __restrict__ wf,
    const unsigned short* __restrict__ wm,
    const float* __restrict__ bf,
    const float* __restrict__ bm,
    float* __restrict__ feat)
{
    __shared__ unsigned short s_b[264 * 64];

    const int tid  = threadIdx.x;
    const int lane = tid & 63;
    const int wv   = tid >> 6;
    const int w0   = blockIdx.x * 64;
    const int h0   = blockIdx.y * 2;
    const int b    = blockIdx.z;

    const int rowsel = wv >> 1;
    const int cohalf = wv & 1;
    const int quad   = lane >> 4;
    const int n15    = lane & 15;

    int rowb[3];
#pragma unroll
    for (int ky = 0; ky < 3; ++ky) rowb[ky] = (rowsel + ky) * 66 + n15;

    // ---- pass A: feature conv2 ----
    STAGE_TILE(t1f);
    __syncthreads();

    float4v acc[2][4];
#pragma unroll
    for (int m = 0; m < 2; ++m)
#pragma unroll
        for (int nt = 0; nt < 4; ++nt) acc[m][nt] = (float4v){0.f, 0.f, 0.f, 0.f};

    {
        const unsigned short* aptr = wf + (((size_t)(cohalf * 2) * 64 + lane) << 3);
        CONV_GEMM(aptr, acc);
    }

    // fp packed bf16 (matches prior rounding when fp was parked as bf16)
    unsigned int fpk[2][4][2];
#pragma unroll
    for (int m = 0; m < 2; ++m) {
        const int mt  = cohalf * 2 + m;
        const int co0 = mt * 16 + quad * 4;
        float4 bv = *(const float4*)&bf[co0];
#pragma unroll
        for (int nt = 0; nt < 4; ++nt) {
            fpk[m][nt][0] = (unsigned int)f2bu(acc[m][nt][0] + bv.x)
                          | ((unsigned int)f2bu(acc[m][nt][1] + bv.y) << 16);
            fpk[m][nt][1] = (unsigned int)f2bu(acc[m][nt][2] + bv.z)
                          | ((unsigned int)f2bu(acc[m][nt][3] + bv.w) << 16);
        }
    }

    __syncthreads();   // all LDS reads of pass A complete

    // ---- pass B: multiplicative conv2 ----
    STAGE_TILE(t1m);
    __syncthreads();

#pragma unroll
    for (int m = 0; m < 2; ++m)
#pragma unroll
        for (int nt = 0; nt < 4; ++nt) acc[m][nt] = (float4v){0.f, 0.f, 0.f, 0.f};

    {
        const unsigned short* aptr = wm + (((size_t)(cohalf * 2) * 64 + lane) << 3);
        CONV_GEMM(aptr, acc);
    }

    const int h = h0 + rowsel;
#pragma unroll
    for (int m = 0; m < 2; ++m) {
        const int mt  = cohalf * 2 + m;
        const int co0 = mt * 16 + quad * 4;
        float4 bv = *(const float4*)&bm[co0];
#pragma unroll
        for (int nt = 0; nt < 4; ++nt) {
            float v[4] = {acc[m][nt][0] + bv.x, acc[m][nt][1] + bv.y,
                          acc[m][nt][2] + bv.z, acc[m][nt][3] + bv.w};
            v[0] *= __uint_as_float((fpk[m][nt][0] & 0xffffu) << 16);
            v[1] *= __uint_as_float(fpk[m][nt][0] & 0xffff0000u);
            v[2] *= __uint_as_float((fpk[m][nt][1] & 0xffffu) << 16);
            v[3] *= __uint_as_float(fpk[m][nt][1] & 0xffff0000u);
#pragma unroll
            for (int r = 0; r < 4; ++r)
                feat[((size_t)b * Cc + co0 + r) * HWc + (size_t)h * Wc + w0 + nt * 16 + n15] = v[r];
        }
    }
}

// ---------------------------------------------------------------------------
// local_fused: lp GEMM pair (49 taps for this block's 64 px -> LDS) + dynamic
// 7x7 local conv + residual. Block tile: 4 rows x 16 cols, all 64 channels.
// grid = (W/16, H/4, B). Phase 1: wave wv = row wv, 16 px/wave, MFMA pair
// with in-LDS relayout (lp_fused logic). Phase 2: thread = 4ch x 4px gather,
// lp read from LDS (broadcast across channel groups).
// ---------------------------------------------------------------------------
__global__ __launch_bounds__(256) void local_fused_k(
    const unsigned short* __restrict__ kfb,
    const unsigned short* __restrict__ w1, const float* __restrict__ b1,
    const unsigned short* __restrict__ w2, const float* __restrict__ b2,
    const float* __restrict__ x, const float* __restrict__ feat,
    float* __restrict__ out)
{
    __shared__ float s_lp[49][68];              // 13328 B, pad 68 -> 2-way max
    __shared__ unsigned short s_t[4 * 1024];    // relayout scratch

    const int tid  = threadIdx.x;
    const int lane = tid & 63;
    const int wv   = tid >> 6;
    const int quad = lane >> 4;
    const int p    = lane & 15;
    const int w0   = blockIdx.x * 16;
    const int h0   = blockIdx.y * 4;
    const int b    = blockIdx.z;

    // ---- phase 1: lp for row h0+wv, cols w0..w0+15 ----
    {
        const size_t pix = ((size_t)b * Hc + h0 + wv) * Wc + w0 + p;
        unsigned short* st = &s_t[wv * 1024];

        float4v acc1[4];
#pragma unroll
        for (int mt = 0; mt < 4; ++mt) acc1[mt] = (float4v){0.f, 0.f, 0.f, 0.f};
#pragma unroll
        for (int s = 0; s < 2; ++s) {
            short8 bfr = *(const short8*)&kfb[pix * Cc + s * 32 + quad * 8];
#pragma unroll
            for (int mt = 0; mt < 4; ++mt) {
                short8 afr = *(const short8*)&w1[(size_t)(((s * 4 + mt) << 6) + lane) << 3];
                acc1[mt] = __builtin_amdgcn_mfma_f32_16x16x32_bf16(afr, bfr, acc1[mt], 0, 0, 0);
            }
        }

#pragma unroll
        for (int mt = 0; mt < 4; ++mt) {
            const int co0 = mt * 16 + quad * 4;
            float4 bv = *(const float4*)&b1[co0];
            ushort4 pk;
            pk.x = f2bu(fmaxf(acc1[mt][0] + bv.x, 0.f));
            pk.y = f2bu(fmaxf(acc1[mt][1] + bv.y, 0.f));
            pk.z = f2bu(fmaxf(acc1[mt][2] + bv.z, 0.f));
            pk.w = f2bu(fmaxf(acc1[mt][3] + bv.w, 0.f));
            const int cg = co0 >> 3;
            *(ushort4*)&st[p * 64 + ((cg ^ (p & 7)) << 3) + (quad & 1) * 4] = pk;
        }
        __syncthreads();

        float4v acc2[4];
#pragma unroll
        for (int mt = 0; mt < 4; ++mt) acc2[mt] = (float4v){0.f, 0.f, 0.f, 0.f};
#pragma unroll
        for (int s = 0; s < 2; ++s) {
            const int cg = s * 4 + quad;
            short8 bfr = *(const short8*)&st[p * 64 + ((cg ^ (p & 7)) << 3)];
#pragma unroll
            for (int mt = 0; mt < 4; ++mt) {
                short8 afr = *(const short8*)&w2[(size_t)(((s * 4 + mt) << 6) + lane) << 3];
                acc2[mt] = __builtin_amdgcn_mfma_f32_16x16x32_bf16(afr, bfr, acc2[mt], 0, 0, 0);
            }
        }

        float v[4][4];
        float partial = 0.f;
#pragma unroll
        for (int mt = 0; mt < 4; ++mt) {
#pragma unroll
            for (int r = 0; r < 4; ++r) {
                const int tap = mt * 16 + quad * 4 + r;
                float val = (tap < 49) ? (acc2[mt][r] + b2[tap]) : 0.f;
                v[mt][r] = val;
                partial += val;
            }
        }
        partial += __shfl_xor(partial, 16, 64);
        partial += __shfl_xor(partial, 32, 64);
        const float mmean = partial * (1.f / 49.f) - (1.f / 49.f);

#pragma unroll
        for (int mt = 0; mt < 4; ++mt) {
#pragma unroll
            for (int r = 0; r < 4; ++r) {
                const int tap = mt * 16 + quad * 4 + r;
                if (tap < 49) s_lp[tap][wv * 16 + p] = v[mt][r] - mmean;
            }
        }
    }
    __syncthreads();

    // ---- phase 2: 7x7 gather + residual ----
    const int cg2 = tid >> 4;                 // 0..15 -> c0 = cg2*4
    const int pg  = tid & 15;
    const int r2  = pg >> 2;
    const int c4  = (pg & 3) * 4;
    const int c0  = cg2 * 4;
    const int h   = h0 + r2;
    const int w4g = w0 + c4;

    float msk[12];
#pragma unroll
    for (int e = 0; e < 12; ++e) {
        int gw = w4g - 4 + e;
        msk[e] = ((unsigned)gw < (unsigned)Wc) ? 1.f : 0.f;
    }

    float acc[4][4];
#pragma unroll
    for (int ch = 0; ch < 4; ++ch)
#pragma unroll
        for (int pq = 0; pq < 4; ++pq) acc[ch][pq] = 0.f;

    const float* fb = feat + ((size_t)b * Cc + c0) * HWc;

#pragma unroll
    for (int dy = 0; dy < 7; ++dy) {
        const int gh = h + dy - 3;
        if ((unsigned)gh >= (unsigned)Hc) continue;

        float4 lp4[7];
#pragma unroll
        for (int dx = 0; dx < 7; ++dx)
            lp4[dx] = *(const float4*)&s_lp[dy * 7 + dx][r2 * 16 + c4];

        const float* frow = fb + (size_t)gh * Wc + w4g;
#pragma unroll
        for (int ch = 0; ch < 4; ++ch) {
            const float* fr = frow + (size_t)ch * HWc;
            float4 a  = *(const float4*)(fr - 4);
            float4 bq = *(const float4*)(fr);
            float4 cq = *(const float4*)(fr + 4);
            float f[12];
            f[0]  = a.x;            f[1]  = a.y * msk[1];
            f[2]  = a.z * msk[2];   f[3]  = a.w * msk[3];
            f[4]  = bq.x;           f[5]  = bq.y;
            f[6]  = bq.z;           f[7]  = bq.w;
            f[8]  = cq.x * msk[8];  f[9]  = cq.y * msk[9];
            f[10] = cq.z * msk[10]; f[11] = cq.w;
#pragma unroll
            for (int dx = 0; dx < 7; ++dx) {
                const float* lpv = (const float*)&lp4[dx];
#pragma unroll
                for (int pq = 0; pq < 4; ++pq)
                    acc[ch][pq] = fmaf(f[pq + dx + 1], lpv[pq], acc[ch][pq]);
            }
        }
    }

#pragma unroll
    for (int ch = 0; ch < 4; ++ch) {
        const size_t idx = ((size_t)b * Cc + c0 + ch) * HWc + (size_t)h * Wc + w4g;
        float4 xv = *(const float4*)&x[idx];
        float4 r  = {acc[ch][0] + xv.x, acc[ch][1] + xv.y,
                     acc[ch][2] + xv.z, acc[ch][3] + xv.w};
        *(float4*)&out[idx] = r;
    }
}

// ---------------------------------------------------------------------------
extern "C" void kernel_launch(void* const* d_in, const int* in_sizes, int n_in,
                              void* d_out, int out_size, void* d_ws, size_t ws_size,
                              hipStream_t stream)
{
    const float* x   = (const float*)d_in[0];
    const float* kf  = (const float*)d_in[1];
    const float* fw1 = (const float*)d_in[2];
    const float* fb1 = (const float*)d_in[3];
    const float* fw2 = (const float*)d_in[4];
    const float* fb2 = (const float*)d_in[5];
    const float* mw1 = (const float*)d_in[6];
    const float* mb1 = (const float*)d_in[7];
    const float* mw2 = (const float*)d_in[8];
    const float* mb2 = (const float*)d_in[9];
    const float* lw1 = (const float*)d_in[10];
    const float* lb1 = (const float*)d_in[11];
    const float* lw2 = (const float*)d_in[12];
    const float* lb2 = (const float*)d_in[13];

    float* out = (float*)d_out;
    char*  ws  = (char*)d_ws;

    const size_t NBH = (size_t)Bc * HWc * Cc * 2;   // bf16 NHWC: 8.4 MB
    const size_t NBF = (size_t)Bc * Cc * HWc * 4;   // f32 NCHW: 16.8 MB

    unsigned short* t1f   = (unsigned short*)(ws);
    unsigned short* t1m   = (unsigned short*)(ws + NBH);
    float*          feat  = (float*)(ws + 2 * NBH);
    unsigned short* xb    = (unsigned short*)(ws + 2 * NBH + NBF);
    unsigned short* kfb   = (unsigned short*)((char*)xb + NBH);
    unsigned short* wbase = (unsigned short*)((char*)kfb + NBH);
    unsigned short* wb1   = wbase;
    unsigned short* wb2   = wbase + 36864;
    unsigned short* wb3   = wbase + 2 * 36864;
    unsigned short* wb4   = wbase + 3 * 36864;
    unsigned short* wl1   = wbase + 4 * 36864;
    unsigned short* wl2   = wbase + 4 * 36864 + 4096;

    dim3 blk(256);
    dim3 gm2(Wc / 64, Hc / 2, Bc * 2);
    dim3 gm (Wc / 64, Hc / 2, Bc);
    dim3 glf(Wc / 16, Hc / 4, Bc);

    cvt_both_k<<<dim3(512), blk, 0, stream>>>(x, kf, xb, kfb);
    wpack_all_k<<<dim3(76), blk, 0, stream>>>(fw1, fw2, mw1, mw2, lw1, lw2, wbase);

    // conv1 of both paths (dual dispatch)
    conv1_dual_k<<<gm2, blk, 0, stream>>>(xb, kfb, wb1, wb3, fb1, mb1, t1f, t1m);

    // conv2 of both paths fused, feat = fp*mp (f32 NCHW)
    conv2_fused_k<<<gm, blk, 0, stream>>>(t1f, t1m, wb2, wb4, fb2, mb2, feat);

    // lp GEMM pair + dynamic local conv + residual, all in one
    local_fused_k<<<glf, blk, 0, stream>>>(kfb, wl1, lb1, wl2, lb2, x, feat, out);
}

// Round 8
// 192.028 us; speedup vs baseline: 1.0573x; 1.0573x over previous
//
#include <hip/hip_runtime.h>
#include <hip/hip_bf16.h>

#define Cc 64
#define Hc 128
#define Wc 128
#define HWc (Hc * Wc)
#define Bc 4

typedef __attribute__((ext_vector_type(8))) short short8;
typedef __attribute__((ext_vector_type(4))) float float4v;

static __device__ __forceinline__ unsigned short f2bu(float f) {
    __hip_bfloat16 h = __float2bfloat16(f);
    return *(unsigned short*)&h;
}

// ---------------------------------------------------------------------------
// Merged NCHW f32 -> NHWC bf16 for x (fused ReLU) and kf. grid = 512.
// ---------------------------------------------------------------------------
__global__ __launch_bounds__(256) void cvt_both_k(
    const float* __restrict__ x, const float* __restrict__ kf,
    unsigned short* __restrict__ xb, unsigned short* __restrict__ kfb)
{
    const int bid = blockIdx.x;
    const bool isx = bid < 256;
    const float* src = isx ? x : kf;
    unsigned short* dst = isx ? xb : kfb;
    const int px = (isx ? bid : bid - 256) * 256 + threadIdx.x;
    const int b  = px >> 14;
    const int hw = px & 16383;
    const float* s = src + (size_t)b * Cc * HWc + hw;
    unsigned short* d = dst + (size_t)px * Cc;

#pragma unroll
    for (int c8 = 0; c8 < 8; ++c8) {
        unsigned int pk[4];
#pragma unroll
        for (int jp = 0; jp < 4; ++jp) {
            float v0 = s[(size_t)(c8 * 8 + jp * 2 + 0) * HWc];
            float v1 = s[(size_t)(c8 * 8 + jp * 2 + 1) * HWc];
            if (isx) { v0 = fmaxf(v0, 0.f); v1 = fmaxf(v1, 0.f); }
            pk[jp] = (unsigned int)f2bu(v0) | ((unsigned int)f2bu(v1) << 16);
        }
        *(uint4*)(d + c8 * 8) = make_uint4(pk[0], pk[1], pk[2], pk[3]);
    }
}

// ---------------------------------------------------------------------------
// All weight packing in one launch.
// ---------------------------------------------------------------------------
__global__ __launch_bounds__(256) void wpack_all_k(
    const float* __restrict__ fw1, const float* __restrict__ fw2,
    const float* __restrict__ mw1, const float* __restrict__ mw2,
    const float* __restrict__ lw1, const float* __restrict__ lw2,
    unsigned short* __restrict__ wbase)
{
    const int bid = blockIdx.x;
    const int tid = threadIdx.x;
    if (bid < 72) {
        const int which = bid / 18;
        const float* w = (which == 0) ? fw1 : (which == 1) ? fw2 : (which == 2) ? mw1 : mw2;
        unsigned short* wb = wbase + (size_t)which * 36864;
        const int g = (bid % 18) * 256 + tid;
        if (g >= 4608) return;
        const int lane = g & 63;
        const int smt  = g >> 6;
        const int s    = smt >> 2;
        const int mt   = smt & 3;
        const int co   = mt * 16 + (lane & 15);
        const int kb   = s * 32 + (lane >> 4) * 8;
        unsigned int pk[4];
#pragma unroll
        for (int jp = 0; jp < 4; ++jp) {
            int k0 = kb + jp * 2, k1 = k0 + 1;
            float v0 = w[((size_t)co * Cc + (k0 & 63)) * 9 + (k0 >> 6)];
            float v1 = w[((size_t)co * Cc + (k1 & 63)) * 9 + (k1 >> 6)];
            pk[jp] = (unsigned int)f2bu(v0) | ((unsigned int)f2bu(v1) << 16);
        }
        *(uint4*)(wb + (size_t)g * 8) = make_uint4(pk[0], pk[1], pk[2], pk[3]);
    } else {
        const int which = (bid - 72) >> 1;
        const float* w = which ? lw2 : lw1;
        const int Cout = which ? 49 : 64;
        unsigned short* wb = wbase + 4 * 36864 + (size_t)which * 4096;
        const int g = ((bid - 72) & 1) * 256 + tid;
        const int lane = g & 63;
        const int smt  = g >> 6;
        const int s    = smt >> 2;
        const int mt   = smt & 3;
        const int co   = mt * 16 + (lane & 15);
        const int kb   = s * 32 + (lane >> 4) * 8;
        unsigned int pk[4];
#pragma unroll
        for (int jp = 0; jp < 4; ++jp) {
            int k0 = kb + jp * 2, k1 = k0 + 1;
            float v0 = (co < Cout) ? w[(size_t)co * Cc + k0] : 0.f;
            float v1 = (co < Cout) ? w[(size_t)co * Cc + k1] : 0.f;
            pk[jp] = (unsigned int)f2bu(v0) | ((unsigned int)f2bu(v1) << 16);
        }
        *(uint4*)(wb + (size_t)g * 8) = make_uint4(pk[0], pk[1], pk[2], pk[3]);
    }
}

// ===== shared staging + pipelined-GEMM building blocks (macros) ============
#define STAGE_TILE(INPTR)                                                     \
    for (int u = tid; u < 264; u += 256) {                                    \
        const int r_  = u / 66;                                               \
        const int c_  = u - r_ * 66;                                          \
        const int gh_ = h0 - 1 + r_;                                          \
        const int gw_ = w0 - 1 + c_;                                          \
        const bool ok_ = ((unsigned)gh_ < (unsigned)Hc) && ((unsigned)gw_ < (unsigned)Wc); \
        const unsigned short* src_ =                                          \
            (INPTR) + (((size_t)b * Hc + (ok_ ? gh_ : 0)) * Wc + (ok_ ? gw_ : 0)) * Cc; \
        const int sw_ = u & 7;                                                \
        _Pragma("unroll")                                                     \
        for (int ch_ = 0; ch_ < 8; ++ch_) {                                   \
            uint4 v_ = ok_ ? *(const uint4*)(src_ + ch_ * 8) : make_uint4(0, 0, 0, 0); \
            *(uint4*)&s_b[u * 64 + ((ch_ ^ sw_) << 3)] = v_;                  \
        }                                                                     \
    }

#define LOAD_A(W, s, m) (*(const short8*)((W) + (size_t)(s) * 2048 + (size_t)(m) * 512))
#define LOAD_B(s, nt) ({                                                      \
        const int tap_ = (s) >> 1;                                            \
        const int qb_  = rowb[tap_ / 3] + tap_ % 3;                           \
        const int ch0_ = ((s) & 1) * 4 + quad;                                \
        *(const short8*)&s_b[(qb_ + (nt) * 16) * 64 + ((ch0_ ^ (qb_ & 7)) << 3)]; })

#define CONV_GEMM(APTR, ACC)                                                  \
    {                                                                         \
        short8 a_cur[2], b_cur[4];                                            \
        _Pragma("unroll")                                                     \
        for (int m = 0; m < 2; ++m) a_cur[m] = LOAD_A(APTR, 0, m);            \
        _Pragma("unroll")                                                     \
        for (int nt = 0; nt < 4; ++nt) b_cur[nt] = LOAD_B(0, nt);             \
        _Pragma("unroll")                                                     \
        for (int s = 0; s < 18; ++s) {                                        \
            short8 a_nxt[2], b_nxt[4];                                        \
            if (s < 17) {                                                     \
                _Pragma("unroll")                                             \
                for (int m = 0; m < 2; ++m) a_nxt[m] = LOAD_A(APTR, s + 1, m);\
                _Pragma("unroll")                                             \
                for (int nt = 0; nt < 4; ++nt) b_nxt[nt] = LOAD_B(s + 1, nt); \
            }                                                                 \
            _Pragma("unroll")                                                 \
            for (int nt = 0; nt < 4; ++nt)                                    \
                _Pragma("unroll")                                             \
                for (int m = 0; m < 2; ++m)                                   \
                    ACC[m][nt] = __builtin_amdgcn_mfma_f32_16x16x32_bf16(     \
                        a_cur[m], b_cur[nt], ACC[m][nt], 0, 0, 0);            \
            if (s < 17) {                                                     \
                _Pragma("unroll")                                             \
                for (int m = 0; m < 2; ++m) a_cur[m] = a_nxt[m];              \
                _Pragma("unroll")                                             \
                for (int nt = 0; nt < 4; ++nt) b_cur[nt] = b_nxt[nt];         \
            }                                                                 \
        }                                                                     \
    }

// ---------------------------------------------------------------------------
// conv1 dual dispatch: both paths' first conv, relu-out, bf16 NHWC out.
// grid = (W/64, H/2, 2*B).
// ---------------------------------------------------------------------------
__global__ __launch_bounds__(256) void conv1_dual_k(
    const unsigned short* __restrict__ in0,
    const unsigned short* __restrict__ in1,
    const unsigned short* __restrict__ wfrag0,
    const unsigned short* __restrict__ wfrag1,
    const float* __restrict__ bias0,
    const float* __restrict__ bias1,
    unsigned short* __restrict__ out0,
    unsigned short* __restrict__ out1)
{
    __shared__ unsigned short s_b[264 * 64];

    const int tid  = threadIdx.x;
    const int lane = tid & 63;
    const int wv   = tid >> 6;
    const int w0   = blockIdx.x * 64;
    const int h0   = blockIdx.y * 2;
    const int zz   = blockIdx.z;
    const int b    = zz & 3;
    const bool sel = zz >> 2;

    const unsigned short* in    = sel ? in1 : in0;
    const unsigned short* wfrag = sel ? wfrag1 : wfrag0;
    const float*          bias  = sel ? bias1 : bias0;
    unsigned short*       out   = sel ? out1 : out0;

    STAGE_TILE(in);
    __syncthreads();

    const int rowsel = wv >> 1;
    const int cohalf = wv & 1;
    const int quad   = lane >> 4;
    const int n15    = lane & 15;
    const unsigned short* aptr = wfrag + (((size_t)(cohalf * 2) * 64 + lane) << 3);

    int rowb[3];
#pragma unroll
    for (int ky = 0; ky < 3; ++ky) rowb[ky] = (rowsel + ky) * 66 + n15;

    float4v acc[2][4];
#pragma unroll
    for (int m = 0; m < 2; ++m)
#pragma unroll
        for (int nt = 0; nt < 4; ++nt) acc[m][nt] = (float4v){0.f, 0.f, 0.f, 0.f};

    CONV_GEMM(aptr, acc);

    const int h = h0 + rowsel;
#pragma unroll
    for (int m = 0; m < 2; ++m) {
        const int mt  = cohalf * 2 + m;
        const int co0 = mt * 16 + quad * 4;
        float4 bv = *(const float4*)&bias[co0];
#pragma unroll
        for (int nt = 0; nt < 4; ++nt) {
            const size_t pix = ((size_t)b * Hc + h) * Wc + w0 + nt * 16 + n15;
            ushort4 pk;
            pk.x = f2bu(fmaxf(acc[m][nt][0] + bv.x, 0.f));
            pk.y = f2bu(fmaxf(acc[m][nt][1] + bv.y, 0.f));
            pk.z = f2bu(fmaxf(acc[m][nt][2] + bv.z, 0.f));
            pk.w = f2bu(fmaxf(acc[m][nt][3] + bv.w, 0.f));
            *(ushort4*)&out[pix * Cc + co0] = pk;
        }
    }
}

// ---------------------------------------------------------------------------
// conv2 fused: fp (regs, bf16-rounded) then mp, feat = fp*mp -> f32 NCHW.
// grid = (W/64, H/2, B).
// ---------------------------------------------------------------------------
__global__ __launch_bounds__(256) void conv2_fused_k(
    const unsigned short* __restrict__ t1f,
    const unsigned short* __restrict__ t1m,
    const unsigned short* __restrict__ wf,
    const unsigned short* __restrict__ wm,
    const float* __restrict__ bf,
    const float* __restrict__ bm,
    float* __restrict__ feat)
{
    __shared__ unsigned short s_b[264 * 64];

    const int tid  = threadIdx.x;
    const int lane = tid & 63;
    const int wv   = tid >> 6;
    const int w0   = blockIdx.x * 64;
    const int h0   = blockIdx.y * 2;
    const int b    = blockIdx.z;

    const int rowsel = wv >> 1;
    const int cohalf = wv & 1;
    const int quad   = lane >> 4;
    const int n15    = lane & 15;

    int rowb[3];
#pragma unroll
    for (int ky = 0; ky < 3; ++ky) rowb[ky] = (rowsel + ky) * 66 + n15;

    STAGE_TILE(t1f);
    __syncthreads();

    float4v acc[2][4];
#pragma unroll
    for (int m = 0; m < 2; ++m)
#pragma unroll
        for (int nt = 0; nt < 4; ++nt) acc[m][nt] = (float4v){0.f, 0.f, 0.f, 0.f};

    {
        const unsigned short* aptr = wf + (((size_t)(cohalf * 2) * 64 + lane) << 3);
        CONV_GEMM(aptr, acc);
    }

    unsigned int fpk[2][4][2];
#pragma unroll
    for (int m = 0; m < 2; ++m) {
        const int mt  = cohalf * 2 + m;
        const int co0 = mt * 16 + quad * 4;
        float4 bv = *(const float4*)&bf[co0];
#pragma unroll
        for (int nt = 0; nt < 4; ++nt) {
            fpk[m][nt][0] = (unsigned int)f2bu(acc[m][nt][0] + bv.x)
                          | ((unsigned int)f2bu(acc[m][nt][1] + bv.y) << 16);
            fpk[m][nt][1] = (unsigned int)f2bu(acc[m][nt][2] + bv.z)
                          | ((unsigned int)f2bu(acc[m][nt][3] + bv.w) << 16);
        }
    }

    __syncthreads();

    STAGE_TILE(t1m);
    __syncthreads();

#pragma unroll
    for (int m = 0; m < 2; ++m)
#pragma unroll
        for (int nt = 0; nt < 4; ++nt) acc[m][nt] = (float4v){0.f, 0.f, 0.f, 0.f};

    {
        const unsigned short* aptr = wm + (((size_t)(cohalf * 2) * 64 + lane) << 3);
        CONV_GEMM(aptr, acc);
    }

    const int h = h0 + rowsel;
#pragma unroll
    for (int m = 0; m < 2; ++m) {
        const int mt  = cohalf * 2 + m;
        const int co0 = mt * 16 + quad * 4;
        float4 bv = *(const float4*)&bm[co0];
#pragma unroll
        for (int nt = 0; nt < 4; ++nt) {
            float v[4] = {acc[m][nt][0] + bv.x, acc[m][nt][1] + bv.y,
                          acc[m][nt][2] + bv.z, acc[m][nt][3] + bv.w};
            v[0] *= __uint_as_float((fpk[m][nt][0] & 0xffffu) << 16);
            v[1] *= __uint_as_float(fpk[m][nt][0] & 0xffff0000u);
            v[2] *= __uint_as_float((fpk[m][nt][1] & 0xffffu) << 16);
            v[3] *= __uint_as_float(fpk[m][nt][1] & 0xffff0000u);
#pragma unroll
            for (int r = 0; r < 4; ++r)
                feat[((size_t)b * Cc + co0 + r) * HWc + (size_t)h * Wc + w0 + nt * 16 + n15] = v[r];
        }
    }
}

// ---------------------------------------------------------------------------
// Fused local-filter path: conv1x1 pair + normalize -> lpb f32 [B][49][HW].
// grid = B*HW/64.
// ---------------------------------------------------------------------------
__global__ __launch_bounds__(256) void lp_fused_k(
    const unsigned short* __restrict__ in,
    const unsigned short* __restrict__ w1,
    const float* __restrict__ b1,
    const unsigned short* __restrict__ w2,
    const float* __restrict__ b2,
    float* __restrict__ out)
{
    __shared__ unsigned short s_t[4 * 1024];

    const int tid  = threadIdx.x;
    const int lane = tid & 63;
    const int wv   = tid >> 6;
    const int quad = lane >> 4;
    const int p    = lane & 15;
    const size_t pix = (size_t)blockIdx.x * 64 + wv * 16 + p;
    unsigned short* st = &s_t[wv * 1024];

    float4v acc1[4];
#pragma unroll
    for (int mt = 0; mt < 4; ++mt) acc1[mt] = (float4v){0.f, 0.f, 0.f, 0.f};
#pragma unroll
    for (int s = 0; s < 2; ++s) {
        short8 bfr = *(const short8*)&in[pix * Cc + s * 32 + quad * 8];
#pragma unroll
        for (int mt = 0; mt < 4; ++mt) {
            short8 afr = *(const short8*)&w1[(size_t)(((s * 4 + mt) << 6) + lane) << 3];
            acc1[mt] = __builtin_amdgcn_mfma_f32_16x16x32_bf16(afr, bfr, acc1[mt], 0, 0, 0);
        }
    }

#pragma unroll
    for (int mt = 0; mt < 4; ++mt) {
        const int co0 = mt * 16 + quad * 4;
        float4 bv = *(const float4*)&b1[co0];
        ushort4 pk;
        pk.x = f2bu(fmaxf(acc1[mt][0] + bv.x, 0.f));
        pk.y = f2bu(fmaxf(acc1[mt][1] + bv.y, 0.f));
        pk.z = f2bu(fmaxf(acc1[mt][2] + bv.z, 0.f));
        pk.w = f2bu(fmaxf(acc1[mt][3] + bv.w, 0.f));
        const int cg = co0 >> 3;
        *(ushort4*)&st[p * 64 + ((cg ^ (p & 7)) << 3) + (quad & 1) * 4] = pk;
    }
    __syncthreads();

    float4v acc2[4];
#pragma unroll
    for (int mt = 0; mt < 4; ++mt) acc2[mt] = (float4v){0.f, 0.f, 0.f, 0.f};
#pragma unroll
    for (int s = 0; s < 2; ++s) {
        const int cg = s * 4 + quad;
        short8 bfr = *(const short8*)&st[p * 64 + ((cg ^ (p & 7)) << 3)];
#pragma unroll
        for (int mt = 0; mt < 4; ++mt) {
            short8 afr = *(const short8*)&w2[(size_t)(((s * 4 + mt) << 6) + lane) << 3];
            acc2[mt] = __builtin_amdgcn_mfma_f32_16x16x32_bf16(afr, bfr, acc2[mt], 0, 0, 0);
        }
    }

    float v[4][4];
    float partial = 0.f;
#pragma unroll
    for (int mt = 0; mt < 4; ++mt) {
#pragma unroll
        for (int r = 0; r < 4; ++r) {
            const int tap = mt * 16 + quad * 4 + r;
            float val = (tap < 49) ? (acc2[mt][r] + b2[tap]) : 0.f;
            v[mt][r] = val;
            partial += val;
        }
    }
    partial += __shfl_xor(partial, 16, 64);
    partial += __shfl_xor(partial, 32, 64);
    const float m = partial * (1.f / 49.f) - (1.f / 49.f);

    const int b  = (int)(pix >> 14);
    const int hw = (int)(pix & 16383);
#pragma unroll
    for (int mt = 0; mt < 4; ++mt) {
#pragma unroll
        for (int r = 0; r < 4; ++r) {
            const int tap = mt * 16 + quad * 4 + r;
            if (tap < 49)
                out[((size_t)b * 49 + tap) * HWc + hw] = v[mt][r] - m;
        }
    }
}

// ---------------------------------------------------------------------------
// Dynamic local 7x7 conv + residual. grid = (C/4, H/8, B): c-group FASTEST so
// the 16 blocks sharing the same 200 KB lp window are dispatch-consecutive
// (same L2 time-window) -> lp HBM traffic ~= compulsory 12.8 MB.
// Block 256 = 32 w-groups x 8 rows; thread = 4ch x 4px.
// ---------------------------------------------------------------------------
__global__ __launch_bounds__(256) void local_conv_v2(
    const float* __restrict__ x, const float* __restrict__ feat,
    const float* __restrict__ lp, float* __restrict__ out)
{
    const int tid = threadIdx.x;
    const int w4  = (tid & 31) * 4;
    const int ro  = tid >> 5;
    const int h   = blockIdx.y * 8 + ro;
    const int c0  = blockIdx.x * 4;
    const int b   = blockIdx.z;

    float msk[12];
#pragma unroll
    for (int e = 0; e < 12; ++e) {
        int gw = w4 - 4 + e;
        msk[e] = ((unsigned)gw < (unsigned)Wc) ? 1.f : 0.f;
    }

    float acc[4][4];
#pragma unroll
    for (int ch = 0; ch < 4; ++ch)
#pragma unroll
        for (int p = 0; p < 4; ++p) acc[ch][p] = 0.f;

    const float* lpb = lp + (size_t)b * 49 * HWc + (size_t)h * Wc + w4;
    const float* fb  = feat + ((size_t)b * Cc + c0) * HWc;

#pragma unroll
    for (int dy = 0; dy < 7; ++dy) {
        const int gh = h + dy - 3;
        if ((unsigned)gh >= (unsigned)Hc) continue;

        float4 lp4[7];
#pragma unroll
        for (int dx = 0; dx < 7; ++dx)
            lp4[dx] = *(const float4*)&lpb[(size_t)(dy * 7 + dx) * HWc];

        const float* frow = fb + (size_t)gh * Wc + w4;
#pragma unroll
        for (int ch = 0; ch < 4; ++ch) {
            const float* fr = frow + (size_t)ch * HWc;
            float4 a  = *(const float4*)(fr - 4);
            float4 bq = *(const float4*)(fr);
            float4 cq = *(const float4*)(fr + 4);
            float f[12];
            f[0]  = a.x;            f[1]  = a.y * msk[1];
            f[2]  = a.z * msk[2];   f[3]  = a.w * msk[3];
            f[4]  = bq.x;           f[5]  = bq.y;
            f[6]  = bq.z;           f[7]  = bq.w;
            f[8]  = cq.x * msk[8];  f[9]  = cq.y * msk[9];
            f[10] = cq.z * msk[10]; f[11] = cq.w;
#pragma unroll
            for (int dx = 0; dx < 7; ++dx) {
                const float* lpv = (const float*)&lp4[dx];
#pragma unroll
                for (int p = 0; p < 4; ++p)
                    acc[ch][p] = fmaf(f[p + dx + 1], lpv[p], acc[ch][p]);
            }
        }
    }

#pragma unroll
    for (int ch = 0; ch < 4; ++ch) {
        const size_t idx = ((size_t)b * Cc + c0 + ch) * HWc + (size_t)h * Wc + w4;
        float4 xv = *(const float4*)&x[idx];
        float4 r  = {acc[ch][0] + xv.x, acc[ch][1] + xv.y,
                     acc[ch][2] + xv.z, acc[ch][3] + xv.w};
        *(float4*)&out[idx] = r;
    }
}

// ---------------------------------------------------------------------------
extern "C" void kernel_launch(void* const* d_in, const int* in_sizes, int n_in,
                              void* d_out, int out_size, void* d_ws, size_t ws_size,
                              hipStream_t stream)
{
    const float* x   = (const float*)d_in[0];
    const float* kf  = (const float*)d_in[1];
    const float* fw1 = (const float*)d_in[2];
    const float* fb1 = (const float*)d_in[3];
    const float* fw2 = (const float*)d_in[4];
    const float* fb2 = (const float*)d_in[5];
    const float* mw1 = (const float*)d_in[6];
    const float* mb1 = (const float*)d_in[7];
    const float* mw2 = (const float*)d_in[8];
    const float* mb2 = (const float*)d_in[9];
    const float* lw1 = (const float*)d_in[10];
    const float* lb1 = (const float*)d_in[11];
    const float* lw2 = (const float*)d_in[12];
    const float* lb2 = (const float*)d_in[13];

    float* out = (float*)d_out;
    char*  ws  = (char*)d_ws;

    const size_t NBH = (size_t)Bc * HWc * Cc * 2;   // bf16 NHWC: 8.4 MB
    const size_t NBF = (size_t)Bc * Cc * HWc * 4;   // f32 NCHW: 16.8 MB
    const size_t LPB = (size_t)Bc * 49 * HWc * 4;   // 12.8 MB

    unsigned short* t1f   = (unsigned short*)(ws);
    unsigned short* t1m   = (unsigned short*)(ws + NBH);
    float*          feat  = (float*)(ws + 2 * NBH);
    float*          lpb   = (float*)(ws + 2 * NBH + NBF);
    unsigned short* xb    = (unsigned short*)(ws + 2 * NBH + NBF + LPB);
    unsigned short* kfb   = (unsigned short*)((char*)xb + NBH);
    unsigned short* wbase = (unsigned short*)((char*)kfb + NBH);
    unsigned short* wb1   = wbase;
    unsigned short* wb2   = wbase + 36864;
    unsigned short* wb3   = wbase + 2 * 36864;
    unsigned short* wb4   = wbase + 3 * 36864;
    unsigned short* wl1   = wbase + 4 * 36864;
    unsigned short* wl2   = wbase + 4 * 36864 + 4096;

    dim3 blk(256);
    dim3 gm2(Wc / 64, Hc / 2, Bc * 2);
    dim3 gm (Wc / 64, Hc / 2, Bc);
    dim3 gp (Bc * HWc / 64);
    dim3 glc(Cc / 4, Hc / 8, Bc);   // c-group fastest for lp L2 locality

    cvt_both_k<<<dim3(512), blk, 0, stream>>>(x, kf, xb, kfb);
    wpack_all_k<<<dim3(76), blk, 0, stream>>>(fw1, fw2, mw1, mw2, lw1, lw2, wbase);

    // conv1 of both paths (dual dispatch)
    conv1_dual_k<<<gm2, blk, 0, stream>>>(xb, kfb, wb1, wb3, fb1, mb1, t1f, t1m);

    // conv2 of both paths fused, feat = fp*mp (f32 NCHW)
    conv2_fused_k<<<gm, blk, 0, stream>>>(t1f, t1m, wb2, wb4, fb2, mb2, feat);

    // local filter path (fused pair) -> lpb
    lp_fused_k<<<gp, blk, 0, stream>>>(kfb, wl1, lb1, wl2, lb2, lpb);

    // dynamic local conv + residual
    local_conv_v2<<<glc, blk, 0, stream>>>(x, feat, lpb, out);
}

// Round 9
// 180.249 us; speedup vs baseline: 1.1264x; 1.0654x over previous
//
#include <hip/hip_runtime.h>
#include <hip/hip_bf16.h>

#define Cc 64
#define Hc 128
#define Wc 128
#define HWc (Hc * Wc)
#define Bc 4

typedef __attribute__((ext_vector_type(8))) short short8;
typedef __attribute__((ext_vector_type(4))) float float4v;

static __device__ __forceinline__ unsigned short f2bu(float f) {
    __hip_bfloat16 h = __float2bfloat16(f);
    return *(unsigned short*)&h;
}

// async global->LDS DMA, 16 B per lane; LDS dest = wave-uniform base + lane*16
static __device__ __forceinline__ void gl_lds16(const void* g, void* l) {
    __builtin_amdgcn_global_load_lds(
        (const __attribute__((address_space(1))) unsigned int*)g,
        (__attribute__((address_space(3))) unsigned int*)l, 16, 0, 0);
}

// ---------------------------------------------------------------------------
// prep: blocks 0..511 = NCHW f32 -> NHWC bf16 (x with ReLU, kf); blocks
// 512..587 = all weight packing. One dispatch.
// ---------------------------------------------------------------------------
__global__ __launch_bounds__(256) void prep_k(
    const float* __restrict__ x, const float* __restrict__ kf,
    const float* __restrict__ fw1, const float* __restrict__ fw2,
    const float* __restrict__ mw1, const float* __restrict__ mw2,
    const float* __restrict__ lw1, const float* __restrict__ lw2,
    unsigned short* __restrict__ xb, unsigned short* __restrict__ kfb,
    unsigned short* __restrict__ wbase)
{
    const int bid = blockIdx.x;
    const int tid = threadIdx.x;

    if (bid < 512) {
        const bool isx = bid < 256;
        const float* src = isx ? x : kf;
        unsigned short* dst = isx ? xb : kfb;
        const int px = (isx ? bid : bid - 256) * 256 + tid;
        const int b  = px >> 14;
        const int hw = px & 16383;
        const float* s = src + (size_t)b * Cc * HWc + hw;
        unsigned short* d = dst + (size_t)px * Cc;
#pragma unroll
        for (int c8 = 0; c8 < 8; ++c8) {
            unsigned int pk[4];
#pragma unroll
            for (int jp = 0; jp < 4; ++jp) {
                float v0 = s[(size_t)(c8 * 8 + jp * 2 + 0) * HWc];
                float v1 = s[(size_t)(c8 * 8 + jp * 2 + 1) * HWc];
                if (isx) { v0 = fmaxf(v0, 0.f); v1 = fmaxf(v1, 0.f); }
                pk[jp] = (unsigned int)f2bu(v0) | ((unsigned int)f2bu(v1) << 16);
            }
            *(uint4*)(d + c8 * 8) = make_uint4(pk[0], pk[1], pk[2], pk[3]);
        }
    } else if (bid < 584) {
        const int wbid  = bid - 512;            // 0..71
        const int which = wbid / 18;
        const float* w = (which == 0) ? fw1 : (which == 1) ? fw2 : (which == 2) ? mw1 : mw2;
        unsigned short* wb = wbase + (size_t)which * 36864;
        const int g = (wbid % 18) * 256 + tid;
        if (g >= 4608) return;
        const int lane = g & 63;
        const int smt  = g >> 6;
        const int s    = smt >> 2;
        const int mt   = smt & 3;
        const int co   = mt * 16 + (lane & 15);
        const int kb   = s * 32 + (lane >> 4) * 8;
        unsigned int pk[4];
#pragma unroll
        for (int jp = 0; jp < 4; ++jp) {
            int k0 = kb + jp * 2, k1 = k0 + 1;
            float v0 = w[((size_t)co * Cc + (k0 & 63)) * 9 + (k0 >> 6)];
            float v1 = w[((size_t)co * Cc + (k1 & 63)) * 9 + (k1 >> 6)];
            pk[jp] = (unsigned int)f2bu(v0) | ((unsigned int)f2bu(v1) << 16);
        }
        *(uint4*)(wb + (size_t)g * 8) = make_uint4(pk[0], pk[1], pk[2], pk[3]);
    } else {
        const int wbid  = bid - 584;            // 0..3
        const int which = wbid >> 1;            // 0: lw1, 1: lw2
        const float* w = which ? lw2 : lw1;
        const int Cout = which ? 49 : 64;
        unsigned short* wb = wbase + 4 * 36864 + (size_t)which * 4096;
        const int g = (wbid & 1) * 256 + tid;
        const int lane = g & 63;
        const int smt  = g >> 6;
        const int s    = smt >> 2;
        const int mt   = smt & 3;
        const int co   = mt * 16 + (lane & 15);
        const int kb   = s * 32 + (lane >> 4) * 8;
        unsigned int pk[4];
#pragma unroll
        for (int jp = 0; jp < 4; ++jp) {
            int k0 = kb + jp * 2, k1 = k0 + 1;
            float v0 = (co < Cout) ? w[(size_t)co * Cc + k0] : 0.f;
            float v1 = (co < Cout) ? w[(size_t)co * Cc + k1] : 0.f;
            pk[jp] = (unsigned int)f2bu(v0) | ((unsigned int)f2bu(v1) << 16);
        }
        *(uint4*)(wb + (size_t)g * 8) = make_uint4(pk[0], pk[1], pk[2], pk[3]);
    }
}

// ===== staging (async DMA, swizzle via lane->channel permutation) ==========
// LDS layout target: s_b[u*64 + ((ch ^ (u&7))<<3)] (shorts). Chunk k = 8
// pixels; lane l = (l>>3)th pixel of chunk, slot j = l&7 -> ch = j ^ (u&7).
#define STAGE_DMA(INPTR, SBUF)                                                \
    for (int k = wv; k < 33; k += 4) {                                        \
        const int u_  = k * 8 + (lane >> 3);                                  \
        const int j_  = lane & 7;                                             \
        const int r_  = u_ / 66;                                              \
        const int c_  = u_ - r_ * 66;                                         \
        const int gh_ = h0 - 1 + r_;                                          \
        const int gw_ = w0 - 1 + c_;                                          \
        const bool ok_ = ((unsigned)gh_ < (unsigned)Hc) && ((unsigned)gw_ < (unsigned)Wc); \
        const int ch_ = j_ ^ (u_ & 7);                                        \
        const unsigned short* g_ = ok_                                        \
            ? (INPTR) + ((((size_t)b * Hc + gh_) * Wc + gw_) << 6) + (ch_ << 3) \
            : zpage + (ch_ << 3);                                             \
        gl_lds16(g_, &(SBUF)[k * 512]);                                       \
    }

#define LOAD_A(W, s, m) (*(const short8*)((W) + (size_t)(s) * 2048 + (size_t)(m) * 512))
#define LOAD_B(SB, s, nt) ({                                                  \
        const int tap_ = (s) >> 1;                                            \
        const int qb_  = rowb[tap_ / 3] + tap_ % 3;                           \
        const int ch0_ = ((s) & 1) * 4 + quad;                                \
        *(const short8*)&(SB)[(qb_ + (nt) * 16) * 64 + ((ch0_ ^ (qb_ & 7)) << 3)]; })

#define CONV_GEMM(APTR, ACC, SB)                                              \
    {                                                                         \
        short8 a_cur[2], b_cur[4];                                            \
        _Pragma("unroll")                                                     \
        for (int m = 0; m < 2; ++m) a_cur[m] = LOAD_A(APTR, 0, m);            \
        _Pragma("unroll")                                                     \
        for (int nt = 0; nt < 4; ++nt) b_cur[nt] = LOAD_B(SB, 0, nt);         \
        _Pragma("unroll")                                                     \
        for (int s = 0; s < 18; ++s) {                                        \
            short8 a_nxt[2], b_nxt[4];                                        \
            if (s < 17) {                                                     \
                _Pragma("unroll")                                             \
                for (int m = 0; m < 2; ++m) a_nxt[m] = LOAD_A(APTR, s + 1, m);\
                _Pragma("unroll")                                             \
                for (int nt = 0; nt < 4; ++nt) b_nxt[nt] = LOAD_B(SB, s + 1, nt); \
            }                                                                 \
            _Pragma("unroll")                                                 \
            for (int nt = 0; nt < 4; ++nt)                                    \
                _Pragma("unroll")                                             \
                for (int m = 0; m < 2; ++m)                                   \
                    ACC[m][nt] = __builtin_amdgcn_mfma_f32_16x16x32_bf16(     \
                        a_cur[m], b_cur[nt], ACC[m][nt], 0, 0, 0);            \
            if (s < 17) {                                                     \
                _Pragma("unroll")                                             \
                for (int m = 0; m < 2; ++m) a_cur[m] = a_nxt[m];              \
                _Pragma("unroll")                                             \
                for (int nt = 0; nt < 4; ++nt) b_cur[nt] = b_nxt[nt];         \
            }                                                                 \
        }                                                                     \
    }

// ---------------------------------------------------------------------------
// conv1 dual: both paths' first conv, relu-out, bf16 NHWC out. DMA staging.
// grid = (W/64, H/2, 2*B).
// ---------------------------------------------------------------------------
__global__ __launch_bounds__(256) void conv1_dual_k(
    const unsigned short* __restrict__ in0,
    const unsigned short* __restrict__ in1,
    const unsigned short* __restrict__ wfrag0,
    const unsigned short* __restrict__ wfrag1,
    const float* __restrict__ bias0,
    const float* __restrict__ bias1,
    const unsigned short* __restrict__ zpage,
    unsigned short* __restrict__ out0,
    unsigned short* __restrict__ out1)
{
    __shared__ unsigned short s_b[264 * 64];

    const int tid  = threadIdx.x;
    const int lane = tid & 63;
    const int wv   = tid >> 6;
    const int w0   = blockIdx.x * 64;
    const int h0   = blockIdx.y * 2;
    const int zz   = blockIdx.z;
    const int b    = zz & 3;
    const bool sel = zz >> 2;

    const unsigned short* in    = sel ? in1 : in0;
    const unsigned short* wfrag = sel ? wfrag1 : wfrag0;
    const float*          bias  = sel ? bias1 : bias0;
    unsigned short*       out   = sel ? out1 : out0;

    STAGE_DMA(in, s_b);
    __syncthreads();

    const int rowsel = wv >> 1;
    const int cohalf = wv & 1;
    const int quad   = lane >> 4;
    const int n15    = lane & 15;
    const unsigned short* aptr = wfrag + (((size_t)(cohalf * 2) * 64 + lane) << 3);

    int rowb[3];
#pragma unroll
    for (int ky = 0; ky < 3; ++ky) rowb[ky] = (rowsel + ky) * 66 + n15;

    float4v acc[2][4];
#pragma unroll
    for (int m = 0; m < 2; ++m)
#pragma unroll
        for (int nt = 0; nt < 4; ++nt) acc[m][nt] = (float4v){0.f, 0.f, 0.f, 0.f};

    CONV_GEMM(aptr, acc, s_b);

    const int h = h0 + rowsel;
#pragma unroll
    for (int m = 0; m < 2; ++m) {
        const int mt  = cohalf * 2 + m;
        const int co0 = mt * 16 + quad * 4;
        float4 bv = *(const float4*)&bias[co0];
#pragma unroll
        for (int nt = 0; nt < 4; ++nt) {
            const size_t pix = ((size_t)b * Hc + h) * Wc + w0 + nt * 16 + n15;
            ushort4 pk;
            pk.x = f2bu(fmaxf(acc[m][nt][0] + bv.x, 0.f));
            pk.y = f2bu(fmaxf(acc[m][nt][1] + bv.y, 0.f));
            pk.z = f2bu(fmaxf(acc[m][nt][2] + bv.z, 0.f));
            pk.w = f2bu(fmaxf(acc[m][nt][3] + bv.w, 0.f));
            *(ushort4*)&out[pix * Cc + co0] = pk;
        }
    }
}

// ---------------------------------------------------------------------------
// conv2 fused: BOTH tiles DMA'd up-front into double LDS, ONE barrier, then
// conv A (fp, bf16-rounded in regs) and conv B (mp) with no intervening
// barrier; feat = fp*mp -> f32 NCHW. grid = (W/64, H/2, B) = 512 = 2/CU,
// so 67.6 KB LDS costs no occupancy.
// ---------------------------------------------------------------------------
__global__ __launch_bounds__(256) void conv2_fused_k(
    const unsigned short* __restrict__ t1f,
    const unsigned short* __restrict__ t1m,
    const unsigned short* __restrict__ wf,
    const unsigned short* __restrict__ wm,
    const float* __restrict__ bf,
    const float* __restrict__ bm,
    const unsigned short* __restrict__ zpage,
    float* __restrict__ feat)
{
    __shared__ unsigned short s_b2[2][264 * 64];

    const int tid  = threadIdx.x;
    const int lane = tid & 63;
    const int wv   = tid >> 6;
    const int w0   = blockIdx.x * 64;
    const int h0   = blockIdx.y * 2;
    const int b    = blockIdx.z;

    STAGE_DMA(t1f, s_b2[0]);
    STAGE_DMA(t1m, s_b2[1]);
    __syncthreads();

    const int rowsel = wv >> 1;
    const int cohalf = wv & 1;
    const int quad   = lane >> 4;
    const int n15    = lane & 15;

    int rowb[3];
#pragma unroll
    for (int ky = 0; ky < 3; ++ky) rowb[ky] = (rowsel + ky) * 66 + n15;

    float4v acc[2][4];
#pragma unroll
    for (int m = 0; m < 2; ++m)
#pragma unroll
        for (int nt = 0; nt < 4; ++nt) acc[m][nt] = (float4v){0.f, 0.f, 0.f, 0.f};

    {
        const unsigned short* aptr = wf + (((size_t)(cohalf * 2) * 64 + lane) << 3);
        CONV_GEMM(aptr, acc, s_b2[0]);
    }

    unsigned int fpk[2][4][2];
#pragma unroll
    for (int m = 0; m < 2; ++m) {
        const int mt  = cohalf * 2 + m;
        const int co0 = mt * 16 + quad * 4;
        float4 bv = *(const float4*)&bf[co0];
#pragma unroll
        for (int nt = 0; nt < 4; ++nt) {
            fpk[m][nt][0] = (unsigned int)f2bu(acc[m][nt][0] + bv.x)
                          | ((unsigned int)f2bu(acc[m][nt][1] + bv.y) << 16);
            fpk[m][nt][1] = (unsigned int)f2bu(acc[m][nt][2] + bv.z)
                          | ((unsigned int)f2bu(acc[m][nt][3] + bv.w) << 16);
        }
    }

#pragma unroll
    for (int m = 0; m < 2; ++m)
#pragma unroll
        for (int nt = 0; nt < 4; ++nt) acc[m][nt] = (float4v){0.f, 0.f, 0.f, 0.f};

    {
        const unsigned short* aptr = wm + (((size_t)(cohalf * 2) * 64 + lane) << 3);
        CONV_GEMM(aptr, acc, s_b2[1]);
    }

    const int h = h0 + rowsel;
#pragma unroll
    for (int m = 0; m < 2; ++m) {
        const int mt  = cohalf * 2 + m;
        const int co0 = mt * 16 + quad * 4;
        float4 bv = *(const float4*)&bm[co0];
#pragma unroll
        for (int nt = 0; nt < 4; ++nt) {
            float v[4] = {acc[m][nt][0] + bv.x, acc[m][nt][1] + bv.y,
                          acc[m][nt][2] + bv.z, acc[m][nt][3] + bv.w};
            v[0] *= __uint_as_float((fpk[m][nt][0] & 0xffffu) << 16);
            v[1] *= __uint_as_float(fpk[m][nt][0] & 0xffff0000u);
            v[2] *= __uint_as_float((fpk[m][nt][1] & 0xffffu) << 16);
            v[3] *= __uint_as_float(fpk[m][nt][1] & 0xffff0000u);
#pragma unroll
            for (int r = 0; r < 4; ++r)
                feat[((size_t)b * Cc + co0 + r) * HWc + (size_t)h * Wc + w0 + nt * 16 + n15] = v[r];
        }
    }
}

// ---------------------------------------------------------------------------
// Fused local-filter path: conv1x1 pair + normalize -> lpb f32 [B][49][HW].
// grid = B*HW/64.
// ---------------------------------------------------------------------------
__global__ __launch_bounds__(256) void lp_fused_k(
    const unsigned short* __restrict__ in,
    const unsigned short* __restrict__ w1,
    const float* __restrict__ b1,
    const unsigned short* __restrict__ w2,
    const float* __restrict__ b2,
    float* __restrict__ out)
{
    __shared__ unsigned short s_t[4 * 1024];

    const int tid  = threadIdx.x;
    const int lane = tid & 63;
    const int wv   = tid >> 6;
    const int quad = lane >> 4;
    const int p    = lane & 15;
    const size_t pix = (size_t)blockIdx.x * 64 + wv * 16 + p;
    unsigned short* st = &s_t[wv * 1024];

    float4v acc1[4];
#pragma unroll
    for (int mt = 0; mt < 4; ++mt) acc1[mt] = (float4v){0.f, 0.f, 0.f, 0.f};
#pragma unroll
    for (int s = 0; s < 2; ++s) {
        short8 bfr = *(const short8*)&in[pix * Cc + s * 32 + quad * 8];
#pragma unroll
        for (int mt = 0; mt < 4; ++mt) {
            short8 afr = *(const short8*)&w1[(size_t)(((s * 4 + mt) << 6) + lane) << 3];
            acc1[mt] = __builtin_amdgcn_mfma_f32_16x16x32_bf16(afr, bfr, acc1[mt], 0, 0, 0);
        }
    }

#pragma unroll
    for (int mt = 0; mt < 4; ++mt) {
        const int co0 = mt * 16 + quad * 4;
        float4 bv = *(const float4*)&b1[co0];
        ushort4 pk;
        pk.x = f2bu(fmaxf(acc1[mt][0] + bv.x, 0.f));
        pk.y = f2bu(fmaxf(acc1[mt][1] + bv.y, 0.f));
        pk.z = f2bu(fmaxf(acc1[mt][2] + bv.z, 0.f));
        pk.w = f2bu(fmaxf(acc1[mt][3] + bv.w, 0.f));
        const int cg = co0 >> 3;
        *(ushort4*)&st[p * 64 + ((cg ^ (p & 7)) << 3) + (quad & 1) * 4] = pk;
    }
    __syncthreads();

    float4v acc2[4];
#pragma unroll
    for (int mt = 0; mt < 4; ++mt) acc2[mt] = (float4v){0.f, 0.f, 0.f, 0.f};
#pragma unroll
    for (int s = 0; s < 2; ++s) {
        const int cg = s * 4 + quad;
        short8 bfr = *(const short8*)&st[p * 64 + ((cg ^ (p & 7)) << 3)];
#pragma unroll
        for (int mt = 0; mt < 4; ++mt) {
            short8 afr = *(const short8*)&w2[(size_t)(((s * 4 + mt) << 6) + lane) << 3];
            acc2[mt] = __builtin_amdgcn_mfma_f32_16x16x32_bf16(afr, bfr, acc2[mt], 0, 0, 0);
        }
    }

    float v[4][4];
    float partial = 0.f;
#pragma unroll
    for (int mt = 0; mt < 4; ++mt) {
#pragma unroll
        for (int r = 0; r < 4; ++r) {
            const int tap = mt * 16 + quad * 4 + r;
            float val = (tap < 49) ? (acc2[mt][r] + b2[tap]) : 0.f;
            v[mt][r] = val;
            partial += val;
        }
    }
    partial += __shfl_xor(partial, 16, 64);
    partial += __shfl_xor(partial, 32, 64);
    const float m = partial * (1.f / 49.f) - (1.f / 49.f);

    const int b  = (int)(pix >> 14);
    const int hw = (int)(pix & 16383);
#pragma unroll
    for (int mt = 0; mt < 4; ++mt) {
#pragma unroll
        for (int r = 0; r < 4; ++r) {
            const int tap = mt * 16 + quad * 4 + r;
            if (tap < 49)
                out[((size_t)b * 49 + tap) * HWc + hw] = v[mt][r] - m;
        }
    }
}

// ---------------------------------------------------------------------------
// Dynamic local 7x7 conv + residual. grid = (C/4, H/8, B), c-group fastest
// for lp L2 locality. Block 256 = 32 w-groups x 8 rows; thread = 4ch x 4px.
// ---------------------------------------------------------------------------
__global__ __launch_bounds__(256) void local_conv_v2(
    const float* __restrict__ x, const float* __restrict__ feat,
    const float* __restrict__ lp, float* __restrict__ out)
{
    const int tid = threadIdx.x;
    const int w4  = (tid & 31) * 4;
    const int ro  = tid >> 5;
    const int h   = blockIdx.y * 8 + ro;
    const int c0  = blockIdx.x * 4;
    const int b   = blockIdx.z;

    float msk[12];
#pragma unroll
    for (int e = 0; e < 12; ++e) {
        int gw = w4 - 4 + e;
        msk[e] = ((unsigned)gw < (unsigned)Wc) ? 1.f : 0.f;
    }

    float acc[4][4];
#pragma unroll
    for (int ch = 0; ch < 4; ++ch)
#pragma unroll
        for (int p = 0; p < 4; ++p) acc[ch][p] = 0.f;

    const float* lpb = lp + (size_t)b * 49 * HWc + (size_t)h * Wc + w4;
    const float* fb  = feat + ((size_t)b * Cc + c0) * HWc;

#pragma unroll
    for (int dy = 0; dy < 7; ++dy) {
        const int gh = h + dy - 3;
        if ((unsigned)gh >= (unsigned)Hc) continue;

        float4 lp4[7];
#pragma unroll
        for (int dx = 0; dx < 7; ++dx)
            lp4[dx] = *(const float4*)&lpb[(size_t)(dy * 7 + dx) * HWc];

        const float* frow = fb + (size_t)gh * Wc + w4;
#pragma unroll
        for (int ch = 0; ch < 4; ++ch) {
            const float* fr = frow + (size_t)ch * HWc;
            float4 a  = *(const float4*)(fr - 4);
            float4 bq = *(const float4*)(fr);
            float4 cq = *(const float4*)(fr + 4);
            float f[12];
            f[0]  = a.x;            f[1]  = a.y * msk[1];
            f[2]  = a.z * msk[2];   f[3]  = a.w * msk[3];
            f[4]  = bq.x;           f[5]  = bq.y;
            f[6]  = bq.z;           f[7]  = bq.w;
            f[8]  = cq.x * msk[8];  f[9]  = cq.y * msk[9];
            f[10] = cq.z * msk[10]; f[11] = cq.w;
#pragma unroll
            for (int dx = 0; dx < 7; ++dx) {
                const float* lpv = (const float*)&lp4[dx];
#pragma unroll
                for (int p = 0; p < 4; ++p)
                    acc[ch][p] = fmaf(f[p + dx + 1], lpv[p], acc[ch][p]);
            }
        }
    }

#pragma unroll
    for (int ch = 0; ch < 4; ++ch) {
        const size_t idx = ((size_t)b * Cc + c0 + ch) * HWc + (size_t)h * Wc + w4;
        float4 xv = *(const float4*)&x[idx];
        float4 r  = {acc[ch][0] + xv.x, acc[ch][1] + xv.y,
                     acc[ch][2] + xv.z, acc[ch][3] + xv.w};
        *(float4*)&out[idx] = r;
    }
}

// ---------------------------------------------------------------------------
extern "C" void kernel_launch(void* const* d_in, const int* in_sizes, int n_in,
                              void* d_out, int out_size, void* d_ws, size_t ws_size,
                              hipStream_t stream)
{
    const float* x   = (const float*)d_in[0];
    const float* kf  = (const float*)d_in[1];
    const float* fw1 = (const float*)d_in[2];
    const float* fb1 = (const float*)d_in[3];
    const float* fw2 = (const float*)d_in[4];
    const float* fb2 = (const float*)d_in[5];
    const float* mw1 = (const float*)d_in[6];
    const float* mb1 = (const float*)d_in[7];
    const float* mw2 = (const float*)d_in[8];
    const float* mb2 = (const float*)d_in[9];
    const float* lw1 = (const float*)d_in[10];
    const float* lb1 = (const float*)d_in[11];
    const float* lw2 = (const float*)d_in[12];
    const float* lb2 = (const float*)d_in[13];

    float* out = (float*)d_out;
    char*  ws  = (char*)d_ws;

    const size_t NBH = (size_t)Bc * HWc * Cc * 2;   // bf16 NHWC: 8.4 MB
    const size_t NBF = (size_t)Bc * Cc * HWc * 4;   // f32 NCHW: 16.8 MB
    const size_t LPB = (size_t)Bc * 49 * HWc * 4;   // 12.8 MB
    const size_t WBA = (size_t)(4 * 36864 + 2 * 4096) * 2;  // packed weights bytes

    unsigned short* t1f   = (unsigned short*)(ws);
    unsigned short* t1m   = (unsigned short*)(ws + NBH);
    float*          feat  = (float*)(ws + 2 * NBH);
    float*          lpb   = (float*)(ws + 2 * NBH + NBF);
    unsigned short* xb    = (unsigned short*)(ws + 2 * NBH + NBF + LPB);
    unsigned short* kfb   = (unsigned short*)((char*)xb + NBH);
    unsigned short* wbase = (unsigned short*)((char*)kfb + NBH);
    unsigned short* zpage = (unsigned short*)((char*)wbase + WBA);
    unsigned short* wb1   = wbase;
    unsigned short* wb2   = wbase + 36864;
    unsigned short* wb3   = wbase + 2 * 36864;
    unsigned short* wb4   = wbase + 3 * 36864;
    unsigned short* wl1   = wbase + 4 * 36864;
    unsigned short* wl2   = wbase + 4 * 36864 + 4096;

    dim3 blk(256);
    dim3 gm2(Wc / 64, Hc / 2, Bc * 2);
    dim3 gm (Wc / 64, Hc / 2, Bc);
    dim3 gp (Bc * HWc / 64);
    dim3 glc(Cc / 4, Hc / 8, Bc);

    // zero page for DMA boundary lanes (ws is poisoned 0xAA each launch)
    hipMemsetAsync(zpage, 0, 256, stream);

    prep_k<<<dim3(588), blk, 0, stream>>>(x, kf, fw1, fw2, mw1, mw2, lw1, lw2,
                                          xb, kfb, wbase);

    conv1_dual_k<<<gm2, blk, 0, stream>>>(xb, kfb, wb1, wb3, fb1, mb1, zpage, t1f, t1m);

    conv2_fused_k<<<gm, blk, 0, stream>>>(t1f, t1m, wb2, wb4, fb2, mb2, zpage, feat);

    lp_fused_k<<<gp, blk, 0, stream>>>(kfb, wl1, lb1, wl2, lb2, lpb);

    local_conv_v2<<<glc, blk, 0, stream>>>(x, feat, lpb, out);
}

// Round 11
// 178.603 us; speedup vs baseline: 1.1367x; 1.0092x over previous
//
#include <hip/hip_runtime.h>
#include <hip/hip_bf16.h>

#define Cc 64
#define Hc 128
#define Wc 128
#define HWc (Hc * Wc)
#define Bc 4

typedef __attribute__((ext_vector_type(8))) short short8;
typedef __attribute__((ext_vector_type(4))) float float4v;

static __device__ __forceinline__ unsigned short f2bu(float f) {
    __hip_bfloat16 h = __float2bfloat16(f);
    return *(unsigned short*)&h;
}

// async global->LDS DMA, 16 B per lane; LDS dest = wave-uniform base + lane*16
static __device__ __forceinline__ void gl_lds16(const void* g, void* l) {
    __builtin_amdgcn_global_load_lds(
        (const __attribute__((address_space(1))) unsigned int*)g,
        (__attribute__((address_space(3))) unsigned int*)l, 16, 0, 0);
}

// ---------------------------------------------------------------------------
// prep: blocks 0..511 = NCHW f32 -> NHWC bf16 (x with ReLU, kf); blocks
// 512..587 = all weight packing. One dispatch.
// ---------------------------------------------------------------------------
__global__ __launch_bounds__(256) void prep_k(
    const float* __restrict__ x, const float* __restrict__ kf,
    const float* __restrict__ fw1, const float* __restrict__ fw2,
    const float* __restrict__ mw1, const float* __restrict__ mw2,
    const float* __restrict__ lw1, const float* __restrict__ lw2,
    unsigned short* __restrict__ xb, unsigned short* __restrict__ kfb,
    unsigned short* __restrict__ wbase)
{
    const int bid = blockIdx.x;
    const int tid = threadIdx.x;

    if (bid < 512) {
        const bool isx = bid < 256;
        const float* src = isx ? x : kf;
        unsigned short* dst = isx ? xb : kfb;
        const int px = (isx ? bid : bid - 256) * 256 + tid;
        const int b  = px >> 14;
        const int hw = px & 16383;
        const float* s = src + (size_t)b * Cc * HWc + hw;
        unsigned short* d = dst + (size_t)px * Cc;
#pragma unroll
        for (int c8 = 0; c8 < 8; ++c8) {
            unsigned int pk[4];
#pragma unroll
            for (int jp = 0; jp < 4; ++jp) {
                float v0 = s[(size_t)(c8 * 8 + jp * 2 + 0) * HWc];
                float v1 = s[(size_t)(c8 * 8 + jp * 2 + 1) * HWc];
                if (isx) { v0 = fmaxf(v0, 0.f); v1 = fmaxf(v1, 0.f); }
                pk[jp] = (unsigned int)f2bu(v0) | ((unsigned int)f2bu(v1) << 16);
            }
            *(uint4*)(d + c8 * 8) = make_uint4(pk[0], pk[1], pk[2], pk[3]);
        }
    } else if (bid < 584) {
        const int wbid  = bid - 512;            // 0..71
        const int which = wbid / 18;
        const float* w = (which == 0) ? fw1 : (which == 1) ? fw2 : (which == 2) ? mw1 : mw2;
        unsigned short* wb = wbase + (size_t)which * 36864;
        const int g = (wbid % 18) * 256 + tid;
        if (g >= 4608) return;
        const int lane = g & 63;
        const int smt  = g >> 6;
        const int s    = smt >> 2;
        const int mt   = smt & 3;
        const int co   = mt * 16 + (lane & 15);
        const int kb   = s * 32 + (lane >> 4) * 8;
        unsigned int pk[4];
#pragma unroll
        for (int jp = 0; jp < 4; ++jp) {
            int k0 = kb + jp * 2, k1 = k0 + 1;
            float v0 = w[((size_t)co * Cc + (k0 & 63)) * 9 + (k0 >> 6)];
            float v1 = w[((size_t)co * Cc + (k1 & 63)) * 9 + (k1 >> 6)];
            pk[jp] = (unsigned int)f2bu(v0) | ((unsigned int)f2bu(v1) << 16);
        }
        *(uint4*)(wb + (size_t)g * 8) = make_uint4(pk[0], pk[1], pk[2], pk[3]);
    } else {
        const int wbid  = bid - 584;            // 0..3
        const int which = wbid >> 1;            // 0: lw1, 1: lw2
        const float* w = which ? lw2 : lw1;
        const int Cout = which ? 49 : 64;
        unsigned short* wb = wbase + 4 * 36864 + (size_t)which * 4096;
        const int g = (wbid & 1) * 256 + tid;
        const int lane = g & 63;
        const int smt  = g >> 6;
        const int s    = smt >> 2;
        const int mt   = smt & 3;
        const int co   = mt * 16 + (lane & 15);
        const int kb   = s * 32 + (lane >> 4) * 8;
        unsigned int pk[4];
#pragma unroll
        for (int jp = 0; jp < 4; ++jp) {
            int k0 = kb + jp * 2, k1 = k0 + 1;
            float v0 = (co < Cout) ? w[(size_t)co * Cc + k0] : 0.f;
            float v1 = (co < Cout) ? w[(size_t)co * Cc + k1] : 0.f;
            pk[jp] = (unsigned int)f2bu(v0) | ((unsigned int)f2bu(v1) << 16);
        }
        *(uint4*)(wb + (size_t)g * 8) = make_uint4(pk[0], pk[1], pk[2], pk[3]);
    }
}

// ===== staging (async DMA, swizzle via lane->channel permutation) ==========
#define STAGE_DMA(INPTR, SBUF)                                                \
    for (int k = wv; k < 33; k += 4) {                                        \
        const int u_  = k * 8 + (lane >> 3);                                  \
        const int j_  = lane & 7;                                             \
        const int r_  = u_ / 66;                                              \
        const int c_  = u_ - r_ * 66;                                         \
        const int gh_ = h0 - 1 + r_;                                          \
        const int gw_ = w0 - 1 + c_;                                          \
        const bool ok_ = ((unsigned)gh_ < (unsigned)Hc) && ((unsigned)gw_ < (unsigned)Wc); \
        const int ch_ = j_ ^ (u_ & 7);                                        \
        const unsigned short* g_ = ok_                                        \
            ? (INPTR) + ((((size_t)b * Hc + gh_) * Wc + gw_) << 6) + (ch_ << 3) \
            : zpage + (ch_ << 3);                                             \
        gl_lds16(g_, &(SBUF)[k * 512]);                                       \
    }

#define LOAD_A(W, s, m) (*(const short8*)((W) + (size_t)(s) * 2048 + (size_t)(m) * 512))
#define LOAD_B(SB, s, nt) ({                                                  \
        const int tap_ = (s) >> 1;                                            \
        const int qb_  = rowb[tap_ / 3] + tap_ % 3;                           \
        const int ch0_ = ((s) & 1) * 4 + quad;                                \
        *(const short8*)&(SB)[(qb_ + (nt) * 16) * 64 + ((ch0_ ^ (qb_ & 7)) << 3)]; })

// Software-pipelined GEMM. A: ring of 4, prefetch distance 3 (write slot
// (s+3)%4 never aliases read slot s%4, and slot was consumed at s-1).
// B: explicit depth-1 cur/nxt (copy AFTER the MFMAs -> no aliasing).
#define CONV_GEMM(APTR, ACC, SB)                                              \
    {                                                                         \
        short8 a_buf[4][2], b_cur[4], b_nxt[4];                               \
        _Pragma("unroll")                                                     \
        for (int q = 0; q < 3; ++q)                                           \
            _Pragma("unroll")                                                 \
            for (int m = 0; m < 2; ++m) a_buf[q][m] = LOAD_A(APTR, q, m);     \
        _Pragma("unroll")                                                     \
        for (int nt = 0; nt < 4; ++nt) b_cur[nt] = LOAD_B(SB, 0, nt);         \
        _Pragma("unroll")                                                     \
        for (int s = 0; s < 18; ++s) {                                        \
            if (s + 3 < 18) {                                                 \
                _Pragma("unroll")                                             \
                for (int m = 0; m < 2; ++m)                                   \
                    a_buf[(s + 3) & 3][m] = LOAD_A(APTR, s + 3, m);           \
            }                                                                 \
            if (s + 1 < 18) {                                                 \
                _Pragma("unroll")                                             \
                for (int nt = 0; nt < 4; ++nt)                                \
                    b_nxt[nt] = LOAD_B(SB, s + 1, nt);                        \
            }                                                                 \
            _Pragma("unroll")                                                 \
            for (int nt = 0; nt < 4; ++nt)                                    \
                _Pragma("unroll")                                             \
                for (int m = 0; m < 2; ++m)                                   \
                    ACC[m][nt] = __builtin_amdgcn_mfma_f32_16x16x32_bf16(     \
                        a_buf[s & 3][m], b_cur[nt], ACC[m][nt], 0, 0, 0);     \
            if (s + 1 < 18) {                                                 \
                _Pragma("unroll")                                             \
                for (int nt = 0; nt < 4; ++nt) b_cur[nt] = b_nxt[nt];         \
            }                                                                 \
        }                                                                     \
    }

// ---------------------------------------------------------------------------
// conv1 + lp merged dispatch. grid = (2, 64, 16):
//   z 0..7  : conv1 of both paths, relu-out, bf16 NHWC.
//   z 8..15 : lp_fused blocks (conv1x1 pair + normalize -> lpb).
// ---------------------------------------------------------------------------
__global__ __launch_bounds__(256) void conv1_lp_k(
    const unsigned short* __restrict__ in0,
    const unsigned short* __restrict__ in1,
    const unsigned short* __restrict__ wfrag0,
    const unsigned short* __restrict__ wfrag1,
    const float* __restrict__ bias0,
    const float* __restrict__ bias1,
    const unsigned short* __restrict__ zpage,
    unsigned short* __restrict__ out0,
    unsigned short* __restrict__ out1,
    const unsigned short* __restrict__ w1, const float* __restrict__ b1,
    const unsigned short* __restrict__ w2, const float* __restrict__ b2,
    float* __restrict__ lpout)
{
    __shared__ unsigned short s_b[264 * 64];

    const int tid  = threadIdx.x;
    const int lane = tid & 63;
    const int wv   = tid >> 6;
    const int quad = lane >> 4;
    const int zz   = blockIdx.z;

    if (zz < 8) {
        // ================= conv1 (dual) =================
        const int w0   = blockIdx.x * 64;
        const int h0   = blockIdx.y * 2;
        const int b    = zz & 3;
        const bool sel = zz >> 2;

        const unsigned short* in    = sel ? in1 : in0;
        const unsigned short* wfrag = sel ? wfrag1 : wfrag0;
        const float*          bias  = sel ? bias1 : bias0;
        unsigned short*       out   = sel ? out1 : out0;

        STAGE_DMA(in, s_b);
        __syncthreads();

        const int rowsel = wv >> 1;
        const int cohalf = wv & 1;
        const int n15    = lane & 15;
        const unsigned short* aptr = wfrag + (((size_t)(cohalf * 2) * 64 + lane) << 3);

        int rowb[3];
#pragma unroll
        for (int ky = 0; ky < 3; ++ky) rowb[ky] = (rowsel + ky) * 66 + n15;

        float4v acc[2][4];
#pragma unroll
        for (int m = 0; m < 2; ++m)
#pragma unroll
            for (int nt = 0; nt < 4; ++nt) acc[m][nt] = (float4v){0.f, 0.f, 0.f, 0.f};

        CONV_GEMM(aptr, acc, s_b);

        const int h = h0 + rowsel;
#pragma unroll
        for (int m = 0; m < 2; ++m) {
            const int mt  = cohalf * 2 + m;
            const int co0 = mt * 16 + quad * 4;
            float4 bv = *(const float4*)&bias[co0];
#pragma unroll
            for (int nt = 0; nt < 4; ++nt) {
                const size_t pix = ((size_t)b * Hc + h) * Wc + w0 + nt * 16 + n15;
                ushort4 pk;
                pk.x = f2bu(fmaxf(acc[m][nt][0] + bv.x, 0.f));
                pk.y = f2bu(fmaxf(acc[m][nt][1] + bv.y, 0.f));
                pk.z = f2bu(fmaxf(acc[m][nt][2] + bv.z, 0.f));
                pk.w = f2bu(fmaxf(acc[m][nt][3] + bv.w, 0.f));
                *(ushort4*)&out[pix * Cc + co0] = pk;
            }
        }
    } else {
        // ================= lp_fused =================
        const int lpid = (zz - 8) * 128 + blockIdx.y * 2 + blockIdx.x;  // 0..1023
        const int p    = lane & 15;
        const size_t pix = (size_t)lpid * 64 + wv * 16 + p;
        unsigned short* st = &s_b[wv * 1024];

        float4v acc1[4];
#pragma unroll
        for (int mt = 0; mt < 4; ++mt) acc1[mt] = (float4v){0.f, 0.f, 0.f, 0.f};
#pragma unroll
        for (int s = 0; s < 2; ++s) {
            short8 bfr = *(const short8*)&in1[pix * Cc + s * 32 + quad * 8];
#pragma unroll
            for (int mt = 0; mt < 4; ++mt) {
                short8 afr = *(const short8*)&w1[(size_t)(((s * 4 + mt) << 6) + lane) << 3];
                acc1[mt] = __builtin_amdgcn_mfma_f32_16x16x32_bf16(afr, bfr, acc1[mt], 0, 0, 0);
            }
        }

#pragma unroll
        for (int mt = 0; mt < 4; ++mt) {
            const int co0 = mt * 16 + quad * 4;
            float4 bv = *(const float4*)&b1[co0];
            ushort4 pk;
            pk.x = f2bu(fmaxf(acc1[mt][0] + bv.x, 0.f));
            pk.y = f2bu(fmaxf(acc1[mt][1] + bv.y, 0.f));
            pk.z = f2bu(fmaxf(acc1[mt][2] + bv.z, 0.f));
            pk.w = f2bu(fmaxf(acc1[mt][3] + bv.w, 0.f));
            const int cg = co0 >> 3;
            *(ushort4*)&st[p * 64 + ((cg ^ (p & 7)) << 3) + (quad & 1) * 4] = pk;
        }
        __syncthreads();

        float4v acc2[4];
#pragma unroll
        for (int mt = 0; mt < 4; ++mt) acc2[mt] = (float4v){0.f, 0.f, 0.f, 0.f};
#pragma unroll
        for (int s = 0; s < 2; ++s) {
            const int cg = s * 4 + quad;
            short8 bfr = *(const short8*)&st[p * 64 + ((cg ^ (p & 7)) << 3)];
#pragma unroll
            for (int mt = 0; mt < 4; ++mt) {
                short8 afr = *(const short8*)&w2[(size_t)(((s * 4 + mt) << 6) + lane) << 3];
                acc2[mt] = __builtin_amdgcn_mfma_f32_16x16x32_bf16(afr, bfr, acc2[mt], 0, 0, 0);
            }
        }

        float v[4][4];
        float partial = 0.f;
#pragma unroll
        for (int mt = 0; mt < 4; ++mt) {
#pragma unroll
            for (int r = 0; r < 4; ++r) {
                const int tap = mt * 16 + quad * 4 + r;
                float val = (tap < 49) ? (acc2[mt][r] + b2[tap]) : 0.f;
                v[mt][r] = val;
                partial += val;
            }
        }
        partial += __shfl_xor(partial, 16, 64);
        partial += __shfl_xor(partial, 32, 64);
        const float m = partial * (1.f / 49.f) - (1.f / 49.f);

        const int b  = (int)(pix >> 14);
        const int hw = (int)(pix & 16383);
#pragma unroll
        for (int mt = 0; mt < 4; ++mt) {
#pragma unroll
            for (int r = 0; r < 4; ++r) {
                const int tap = mt * 16 + quad * 4 + r;
                if (tap < 49)
                    lpout[((size_t)b * 49 + tap) * HWc + hw] = v[mt][r] - m;
            }
        }
    }
}

// ---------------------------------------------------------------------------
// conv2 fused: BOTH tiles DMA'd up-front, ONE barrier, two GEMMs, feat=fp*mp.
// grid = (W/64, H/2, B).
// ---------------------------------------------------------------------------
__global__ __launch_bounds__(256) void conv2_fused_k(
    const unsigned short* __restrict__ t1f,
    const unsigned short* __restrict__ t1m,
    const unsigned short* __restrict__ wf,
    const unsigned short* __restrict__ wm,
    const float* __restrict__ bf,
    const float* __restrict__ bm,
    const unsigned short* __restrict__ zpage,
    float* __restrict__ feat)
{
    __shared__ unsigned short s_b2[2][264 * 64];

    const int tid  = threadIdx.x;
    const int lane = tid & 63;
    const int wv   = tid >> 6;
    const int w0   = blockIdx.x * 64;
    const int h0   = blockIdx.y * 2;
    const int b    = blockIdx.z;

    STAGE_DMA(t1f, s_b2[0]);
    STAGE_DMA(t1m, s_b2[1]);
    __syncthreads();

    const int rowsel = wv >> 1;
    const int cohalf = wv & 1;
    const int quad   = lane >> 4;
    const int n15    = lane & 15;

    int rowb[3];
#pragma unroll
    for (int ky = 0; ky < 3; ++ky) rowb[ky] = (rowsel + ky) * 66 + n15;

    float4v acc[2][4];
#pragma unroll
    for (int m = 0; m < 2; ++m)
#pragma unroll
        for (int nt = 0; nt < 4; ++nt) acc[m][nt] = (float4v){0.f, 0.f, 0.f, 0.f};

    {
        const unsigned short* aptr = wf + (((size_t)(cohalf * 2) * 64 + lane) << 3);
        CONV_GEMM(aptr, acc, s_b2[0]);
    }

    unsigned int fpk[2][4][2];
#pragma unroll
    for (int m = 0; m < 2; ++m) {
        const int mt  = cohalf * 2 + m;
        const int co0 = mt * 16 + quad * 4;
        float4 bv = *(const float4*)&bf[co0];
#pragma unroll
        for (int nt = 0; nt < 4; ++nt) {
            fpk[m][nt][0] = (unsigned int)f2bu(acc[m][nt][0] + bv.x)
                          | ((unsigned int)f2bu(acc[m][nt][1] + bv.y) << 16);
            fpk[m][nt][1] = (unsigned int)f2bu(acc[m][nt][2] + bv.z)
                          | ((unsigned int)f2bu(acc[m][nt][3] + bv.w) << 16);
        }
    }

#pragma unroll
    for (int m = 0; m < 2; ++m)
#pragma unroll
        for (int nt = 0; nt < 4; ++nt) acc[m][nt] = (float4v){0.f, 0.f, 0.f, 0.f};

    {
        const unsigned short* aptr = wm + (((size_t)(cohalf * 2) * 64 + lane) << 3);
        CONV_GEMM(aptr, acc, s_b2[1]);
    }

    const int h = h0 + rowsel;
#pragma unroll
    for (int m = 0; m < 2; ++m) {
        const int mt  = cohalf * 2 + m;
        const int co0 = mt * 16 + quad * 4;
        float4 bv = *(const float4*)&bm[co0];
#pragma unroll
        for (int nt = 0; nt < 4; ++nt) {
            float v[4] = {acc[m][nt][0] + bv.x, acc[m][nt][1] + bv.y,
                          acc[m][nt][2] + bv.z, acc[m][nt][3] + bv.w};
            v[0] *= __uint_as_float((fpk[m][nt][0] & 0xffffu) << 16);
            v[1] *= __uint_as_float(fpk[m][nt][0] & 0xffff0000u);
            v[2] *= __uint_as_float((fpk[m][nt][1] & 0xffffu) << 16);
            v[3] *= __uint_as_float(fpk[m][nt][1] & 0xffff0000u);
#pragma unroll
            for (int r = 0; r < 4; ++r)
                feat[((size_t)b * Cc + co0 + r) * HWc + (size_t)h * Wc + w0 + nt * 16 + n15] = v[r];
        }
    }
}

// ---------------------------------------------------------------------------
// Dynamic local 7x7 conv + residual. grid = (C/4, H/8, B), c-group fastest.
// ---------------------------------------------------------------------------
__global__ __launch_bounds__(256) void local_conv_v2(
    const float* __restrict__ x, const float* __restrict__ feat,
    const float* __restrict__ lp, float* __restrict__ out)
{
    const int tid = threadIdx.x;
    const int w4  = (tid & 31) * 4;
    const int ro  = tid >> 5;
    const int h   = blockIdx.y * 8 + ro;
    const int c0  = blockIdx.x * 4;
    const int b   = blockIdx.z;

    float msk[12];
#pragma unroll
    for (int e = 0; e < 12; ++e) {
        int gw = w4 - 4 + e;
        msk[e] = ((unsigned)gw < (unsigned)Wc) ? 1.f : 0.f;
    }

    float acc[4][4];
#pragma unroll
    for (int ch = 0; ch < 4; ++ch)
#pragma unroll
        for (int p = 0; p < 4; ++p) acc[ch][p] = 0.f;

    const float* lpb = lp + (size_t)b * 49 * HWc + (size_t)h * Wc + w4;
    const float* fb  = feat + ((size_t)b * Cc + c0) * HWc;

#pragma unroll
    for (int dy = 0; dy < 7; ++dy) {
        const int gh = h + dy - 3;
        if ((unsigned)gh >= (unsigned)Hc) continue;

        float4 lp4[7];
#pragma unroll
        for (int dx = 0; dx < 7; ++dx)
            lp4[dx] = *(const float4*)&lpb[(size_t)(dy * 7 + dx) * HWc];

        const float* frow = fb + (size_t)gh * Wc + w4;
#pragma unroll
        for (int ch = 0; ch < 4; ++ch) {
            const float* fr = frow + (size_t)ch * HWc;
            float4 a  = *(const float4*)(fr - 4);
            float4 bq = *(const float4*)(fr);
            float4 cq = *(const float4*)(fr + 4);
            float f[12];
            f[0]  = a.x;            f[1]  = a.y * msk[1];
            f[2]  = a.z * msk[2];   f[3]  = a.w * msk[3];
            f[4]  = bq.x;           f[5]  = bq.y;
            f[6]  = bq.z;           f[7]  = bq.w;
            f[8]  = cq.x * msk[8];  f[9]  = cq.y * msk[9];
            f[10] = cq.z * msk[10]; f[11] = cq.w;
#pragma unroll
            for (int dx = 0; dx < 7; ++dx) {
                const float* lpv = (const float*)&lp4[dx];
#pragma unroll
                for (int p = 0; p < 4; ++p)
                    acc[ch][p] = fmaf(f[p + dx + 1], lpv[p], acc[ch][p]);
            }
        }
    }

#pragma unroll
    for (int ch = 0; ch < 4; ++ch) {
        const size_t idx = ((size_t)b * Cc + c0 + ch) * HWc + (size_t)h * Wc + w4;
        float4 xv = *(const float4*)&x[idx];
        float4 r  = {acc[ch][0] + xv.x, acc[ch][1] + xv.y,
                     acc[ch][2] + xv.z, acc[ch][3] + xv.w};
        *(float4*)&out[idx] = r;
    }
}

// ---------------------------------------------------------------------------
extern "C" void kernel_launch(void* const* d_in, const int* in_sizes, int n_in,
                              void* d_out, int out_size, void* d_ws, size_t ws_size,
                              hipStream_t stream)
{
    const float* x   = (const float*)d_in[0];
    const float* kf  = (const float*)d_in[1];
    const float* fw1 = (const float*)d_in[2];
    const float* fb1 = (const float*)d_in[3];
    const float* fw2 = (const float*)d_in[4];
    const float* fb2 = (const float*)d_in[5];
    const float* mw1 = (const float*)d_in[6];
    const float* mb1 = (const float*)d_in[7];
    const float* mw2 = (const float*)d_in[8];
    const float* mb2 = (const float*)d_in[9];
    const float* lw1 = (const float*)d_in[10];
    const float* lb1 = (const float*)d_in[11];
    const float* lw2 = (const float*)d_in[12];
    const float* lb2 = (const float*)d_in[13];

    float* out = (float*)d_out;
    char*  ws  = (char*)d_ws;

    const size_t NBH = (size_t)Bc * HWc * Cc * 2;   // bf16 NHWC: 8.4 MB
    const size_t NBF = (size_t)Bc * Cc * HWc * 4;   // f32 NCHW: 16.8 MB
    const size_t LPB = (size_t)Bc * 49 * HWc * 4;   // 12.8 MB
    const size_t WBA = (size_t)(4 * 36864 + 2 * 4096) * 2;

    unsigned short* t1f   = (unsigned short*)(ws);
    unsigned short* t1m   = (unsigned short*)(ws + NBH);
    float*          feat  = (float*)(ws + 2 * NBH);
    float*          lpb   = (float*)(ws + 2 * NBH + NBF);
    unsigned short* xb    = (unsigned short*)(ws + 2 * NBH + NBF + LPB);
    unsigned short* kfb   = (unsigned short*)((char*)xb + NBH);
    unsigned short* wbase = (unsigned short*)((char*)kfb + NBH);
    unsigned short* zpage = (unsigned short*)((char*)wbase + WBA);
    unsigned short* wb1   = wbase;
    unsigned short* wb2   = wbase + 36864;
    unsigned short* wb3   = wbase + 2 * 36864;
    unsigned short* wb4   = wbase + 3 * 36864;
    unsigned short* wl1   = wbase + 4 * 36864;
    unsigned short* wl2   = wbase + 4 * 36864 + 4096;

    dim3 blk(256);
    dim3 gc1(Wc / 64, Hc / 2, 16);   // z 0..7 conv1 dual, z 8..15 lp blocks
    dim3 gm (Wc / 64, Hc / 2, Bc);
    dim3 glc(Cc / 4, Hc / 8, Bc);

    hipMemsetAsync(zpage, 0, 256, stream);

    prep_k<<<dim3(588), blk, 0, stream>>>(x, kf, fw1, fw2, mw1, mw2, lw1, lw2,
                                          xb, kfb, wbase);

    conv1_lp_k<<<gc1, blk, 0, stream>>>(xb, kfb, wb1, wb3, fb1, mb1, zpage,
                                        t1f, t1m, wl1, lb1, wl2, lb2, lpb);

    conv2_fused_k<<<gm, blk, 0, stream>>>(t1f, t1m, wb2, wb4, fb2, mb2, zpage, feat);

    local_conv_v2<<<glc, blk, 0, stream>>>(x, feat, lpb, out);
}